// Round 1
// baseline (6768.973 us; speedup 1.0000x reference)
//
#include <hip/hip_runtime.h>
#include <math.h>

#define Bsz 512
#define Lm  128
#define Mn  6
#define AD  39
#define BDm 10
#define F   256
#define TB  16
#define NR  (TB*Mn)      // 96 neighbor rows per tile
#define NTHREADS 256

__device__ __forceinline__ float lrelu(float x){ return x > 0.0f ? x : 0.01f*x; }
__device__ __forceinline__ float sigm(float x){ return 1.0f/(1.0f+expf(-x)); }

// LDS region offsets (bytes), manually aliased:
//   [0, 98688)          nf[96][257]            ... later aliased by afT[256][16] (16384 B)
//   [98688, 120000)     arow[16][39]+nA[96][39]+nB[96][10]  ... later aliased by ctx[256][16]
//   [120000, 136448)    af[16][257]
//   [136448, 152832)    wn[256][16]
//   [152832, 154496)    adeg[96], bdeg[96], ascore[16], nscore[96], aw[96], sumaw[16]
#define OFF_NF    0
#define OFF_AROW  98688
#define OFF_NA    101184
#define OFF_NB    116160
#define OFF_CTX   98688
#define OFF_AF    120000
#define OFF_WN    136448
#define OFF_ADEG  152832
#define OFF_BDEG  153216
#define OFF_AS    153600
#define OFF_NS    153664
#define OFF_AW    154048
#define OFF_SUM   154432
#define SMEM_BYTES 154496

__global__ __launch_bounds__(NTHREADS)
void fp_fused_kernel(const float* __restrict__ atom_list,
                     const float* __restrict__ bond_list,
                     const int*   __restrict__ adeg_g,
                     const int*   __restrict__ bdeg_g,
                     const float* __restrict__ W_atom, const float* __restrict__ b_atom,
                     const float* __restrict__ W_nbr,  const float* __restrict__ b_nbr,
                     const float* __restrict__ W_align,const float* __restrict__ b_align,
                     const float* __restrict__ W_att,  const float* __restrict__ b_att,
                     const float* __restrict__ W_ih,   const float* __restrict__ b_ih,
                     const float* __restrict__ W_hh,   const float* __restrict__ b_hh,
                     float* __restrict__ out)
{
    __shared__ alignas(16) char smem[SMEM_BYTES];
    float (*nf)[F+1]   = (float (*)[F+1])(smem + OFF_NF);    // [96][257]
    float (*afT)[TB]   = (float (*)[TB]) (smem + OFF_NF);    // [256][16] alias (valid after E2)
    float (*arow)[AD]  = (float (*)[AD]) (smem + OFF_AROW);  // [16][39]
    float (*nA)[AD]    = (float (*)[AD]) (smem + OFF_NA);    // [96][39]
    float (*nB)[BDm]   = (float (*)[BDm])(smem + OFF_NB);    // [96][10]
    float (*ctx)[TB]   = (float (*)[TB]) (smem + OFF_CTX);   // [256][16] alias (phase F+)
    float (*af)[F+1]   = (float (*)[F+1])(smem + OFF_AF);    // [16][257]
    float (*wn)[TB]    = (float (*)[TB]) (smem + OFF_WN);    // [256][16]
    int*   adeg        = (int*)  (smem + OFF_ADEG);          // [96]
    int*   bdeg        = (int*)  (smem + OFF_BDEG);          // [96]
    float* ascore      = (float*)(smem + OFF_AS);            // [16]
    float* nscore      = (float*)(smem + OFF_NS);            // [96]
    float* aw          = (float*)(smem + OFF_AW);            // [96]  ([a][m])
    float* sumaw       = (float*)(smem + OFF_SUM);           // [16]

    const int t       = threadIdx.x;
    const int g0      = blockIdx.x * TB;   // global atom-row base
    const int molbase = (g0 / Lm) * Lm;

    // ---------------- Phase A: degree lists + own atom rows + gathers ----------------
    if (t < NR) {
        adeg[t] = adeg_g[g0*Mn + t];
        bdeg[t] = bdeg_g[g0*Mn + t];
    }
    for (int i = t; i < TB*AD; i += NTHREADS)
        ((float*)arow)[i] = atom_list[g0*AD + i];            // contiguous 624 floats
    __syncthreads();
    for (int i = t; i < NR*AD; i += NTHREADS) {
        int r = i / AD, d = i - r*AD;
        nA[r][d] = atom_list[(molbase + adeg[r])*AD + d];
    }
    for (int i = t; i < NR*BDm; i += NTHREADS) {
        int r = i / BDm, d = i - r*BDm;
        nB[r][d] = bond_list[(molbase + bdeg[r])*BDm + d];
    }
    __syncthreads();

    // ---------------- Phase B: atom_feature = lrelu(arow @ W_atom^T + b) ----------------
    {
        float w[AD];
        #pragma unroll
        for (int d = 0; d < AD; ++d) w[d] = W_atom[t*AD + d];
        const float bb = b_atom[t];
        for (int a = 0; a < TB; ++a) {
            float acc = bb;
            #pragma unroll
            for (int d = 0; d < AD; ++d) acc += arow[a][d]*w[d];
            af[a][t] = lrelu(acc);
        }
    }
    // ---------------- Phase C: neighbor_feature = lrelu([nA|nB] @ W_nbr^T + b) ----------------
    {
        float w[AD+BDm];
        #pragma unroll
        for (int d = 0; d < AD+BDm; ++d) w[d] = W_nbr[t*(AD+BDm) + d];
        const float bb = b_nbr[t];
        for (int r = 0; r < NR; ++r) {
            float acc = bb;
            #pragma unroll
            for (int d = 0; d < AD; ++d)  acc += nA[r][d]*w[d];
            #pragma unroll
            for (int d = 0; d < BDm; ++d) acc += nB[r][d]*w[AD+d];
            nf[r][t] = lrelu(acc);
        }
    }
    __syncthreads();

    // ---------------- Phase D: align-score partial dots ----------------
    if (t < TB) {
        float acc = 0.f;
        for (int k = 0; k < F; ++k) acc += af[t][k]*W_align[k];
        ascore[t] = acc;
    } else if (t < TB + NR) {
        const int r = t - TB;
        float acc = 0.f;
        for (int k = 0; k < F; ++k) acc += nf[r][k]*W_align[F+k];
        nscore[r] = acc;
    }
    __syncthreads();

    // ---------------- Phase E: masked softmax over m ----------------
    if (t < TB) {
        const float ba = b_align[0];
        float sc[Mn], msk[Mn];
        float mx = -1e30f;
        #pragma unroll
        for (int m = 0; m < Mn; ++m) {
            const int pad = (adeg[t*Mn+m] == Lm-1);
            float s = lrelu(ascore[t] + nscore[t*Mn+m] + ba) + (pad ? -9e8f : 0.0f);
            msk[m] = pad ? 0.f : 1.f;
            sc[m] = s; mx = fmaxf(mx, s);
        }
        float sum = 0.f;
        #pragma unroll
        for (int m = 0; m < Mn; ++m) { sc[m] = expf(sc[m]-mx); sum += sc[m]; }
        const float inv = 1.0f/sum;
        float sa = 0.f;
        #pragma unroll
        for (int m = 0; m < Mn; ++m) { float w = sc[m]*inv*msk[m]; aw[t*Mn+m] = w; sa += w; }
        sumaw[t] = sa;
    }
    __syncthreads();

    // ---------------- Phase E2: wn[k][a] = sum_m aw[a][m]*nf[a*6+m][k] ----------------
    for (int a = 0; a < TB; ++a) {
        float acc = 0.f;
        #pragma unroll
        for (int m = 0; m < Mn; ++m) acc += aw[a*Mn+m]*nf[a*Mn+m][t];
        wn[t][a] = acc;
    }
    __syncthreads();

    // ---------------- Phase F: transpose af; context = elu(wn @ W_att^T + b*sumaw) ----------------
    {
        for (int a = 0; a < TB; ++a) afT[t][a] = af[a][t];   // afT aliases dead nf
        float acc[TB];
        const float bb = b_att[t];
        #pragma unroll
        for (int a = 0; a < TB; ++a) acc[a] = bb*sumaw[a];
        for (int k = 0; k < F; ++k) {
            const float w = W_att[t*F + k];
            const float4* wp = (const float4*)(&wn[k][0]);
            #pragma unroll
            for (int q = 0; q < 4; ++q) {
                float4 v = wp[q];
                acc[4*q+0] += v.x*w; acc[4*q+1] += v.y*w;
                acc[4*q+2] += v.z*w; acc[4*q+3] += v.w*w;
            }
        }
        #pragma unroll
        for (int a = 0; a < TB; ++a) {
            float x = acc[a];
            ctx[t][a] = (x > 0.f) ? x : expm1f(x);           // elu; ctx aliases dead gather region
        }
    }
    __syncthreads();

    // ---------------- Phase G: GRU cell + relu, fully per-thread over feature f=t ----------------
    {
        float aIR[TB], aIZ[TB], aIN[TB], aHR[TB], aHZ[TB], aHN[TB];
        const float bir = b_ih[t], biz = b_ih[F+t], bin_ = b_ih[2*F+t];
        const float bhr = b_hh[t], bhz = b_hh[F+t], bhn  = b_hh[2*F+t];
        #pragma unroll
        for (int a = 0; a < TB; ++a) {
            aIR[a]=bir; aIZ[a]=biz; aIN[a]=bin_;
            aHR[a]=bhr; aHZ[a]=bhz; aHN[a]=bhn;
        }
        for (int k = 0; k < F; ++k) {
            const float wir = W_ih[t*F+k], wiz = W_ih[(F+t)*F+k], win = W_ih[(2*F+t)*F+k];
            const float whr = W_hh[t*F+k], whz = W_hh[(F+t)*F+k], whn = W_hh[(2*F+t)*F+k];
            const float4* cp = (const float4*)(&ctx[k][0]);
            const float4* hp = (const float4*)(&afT[k][0]);
            #pragma unroll
            for (int q = 0; q < 4; ++q) {
                float4 c = cp[q]; float4 h = hp[q];
                const int a0 = 4*q;
                aIR[a0+0]+=c.x*wir; aIR[a0+1]+=c.y*wir; aIR[a0+2]+=c.z*wir; aIR[a0+3]+=c.w*wir;
                aIZ[a0+0]+=c.x*wiz; aIZ[a0+1]+=c.y*wiz; aIZ[a0+2]+=c.z*wiz; aIZ[a0+3]+=c.w*wiz;
                aIN[a0+0]+=c.x*win; aIN[a0+1]+=c.y*win; aIN[a0+2]+=c.z*win; aIN[a0+3]+=c.w*win;
                aHR[a0+0]+=h.x*whr; aHR[a0+1]+=h.y*whr; aHR[a0+2]+=h.z*whr; aHR[a0+3]+=h.w*whr;
                aHZ[a0+0]+=h.x*whz; aHZ[a0+1]+=h.y*whz; aHZ[a0+2]+=h.z*whz; aHZ[a0+3]+=h.w*whz;
                aHN[a0+0]+=h.x*whn; aHN[a0+1]+=h.y*whn; aHN[a0+2]+=h.z*whn; aHN[a0+3]+=h.w*whn;
            }
        }
        for (int a = 0; a < TB; ++a) {
            const float r = sigm(aIR[a]+aHR[a]);
            const float z = sigm(aIZ[a]+aHZ[a]);
            const float n = tanhf(aIN[a] + r*aHN[a]);
            const float hprev = af[a][t];
            const float h = (1.f - z)*n + z*hprev;
            out[(size_t)(g0+a)*F + t] = fmaxf(h, 0.f);
        }
    }
}

extern "C" void kernel_launch(void* const* d_in, const int* in_sizes, int n_in,
                              void* d_out, int out_size, void* d_ws, size_t ws_size,
                              hipStream_t stream) {
    const float* atom_list = (const float*)d_in[0];
    const float* bond_list = (const float*)d_in[1];
    const int*   adeg      = (const int*)  d_in[2];
    const int*   bdeg      = (const int*)  d_in[3];
    // d_in[4] = atom_mask (unused by the reference computation)
    const float* W_atom  = (const float*)d_in[5];
    const float* b_atom  = (const float*)d_in[6];
    const float* W_nbr   = (const float*)d_in[7];
    const float* b_nbr   = (const float*)d_in[8];
    const float* W_align = (const float*)d_in[9];
    const float* b_align = (const float*)d_in[10];
    const float* W_att   = (const float*)d_in[11];
    const float* b_att   = (const float*)d_in[12];
    const float* W_ih    = (const float*)d_in[13];
    const float* b_ih    = (const float*)d_in[14];
    const float* W_hh    = (const float*)d_in[15];
    const float* b_hh    = (const float*)d_in[16];
    float* out = (float*)d_out;

    const int nblocks = (Bsz*Lm)/TB;   // 4096
    fp_fused_kernel<<<nblocks, NTHREADS, 0, stream>>>(
        atom_list, bond_list, adeg, bdeg,
        W_atom, b_atom, W_nbr, b_nbr, W_align, b_align,
        W_att, b_att, W_ih, b_ih, W_hh, b_hh, out);
}

// Round 2
// 652.912 us; speedup vs baseline: 10.3674x; 10.3674x over previous
//
#include <hip/hip_runtime.h>
#include <math.h>

#define Bsz 512
#define Lm  128
#define Mn  6
#define AD  39
#define BDm 10
#define KN  49          // AD+BDm
#define KNP 64          // padded K for neighbor GEMM
#define F   256
#define TB  16
#define NR  96          // TB*Mn
#define NT  256

// ws byte offsets
#define WS_WNBR 0
#define WS_WATT 32768
#define WS_WIH  163840
#define WS_WHH  557056
#define WS_AF   950272
#define WS_ASC  34504704
#define WS_SUM  34766848
#define WS_WN   35028992
// end: 68583424 bytes (~65.4 MB)

typedef __attribute__((ext_vector_type(8))) short bf16x8;
typedef __attribute__((ext_vector_type(4))) float f32x4;

__device__ __forceinline__ float lrelu(float x){ return x > 0.0f ? x : 0.01f*x; }
__device__ __forceinline__ float sigm(float x){ return 1.0f/(1.0f+expf(-x)); }
__device__ __forceinline__ unsigned short f2bf(float f){
    unsigned int u = __builtin_bit_cast(unsigned int, f);
    u += 0x7fffu + ((u>>16)&1u);
    return (unsigned short)(u>>16);
}
__device__ __forceinline__ float bf2f(unsigned short h){
    unsigned int u = ((unsigned int)h)<<16;
    return __builtin_bit_cast(float, u);
}

// ---------------- P0: weights -> bf16 fragment-major ----------------
// frag layout per 16x16x32 tile: elem e = lane*8 + j; n = nt*16 + (lane&15),
// k = ks*32 + (lane>>4)*8 + j.  tile order T_mat = nt*ksteps + ks.
__global__ __launch_bounds__(NT)
void p0_prep(const float* __restrict__ Wnbr, const float* __restrict__ Watt,
             const float* __restrict__ Wih,  const float* __restrict__ Whh,
             unsigned short* __restrict__ ws)
{
    int id = blockIdx.x*NT + threadIdx.x;
    if (id >= 928*512) return;
    int T = id >> 9, e = id & 511;
    int lane = e >> 3, j = e & 7;
    int col16 = lane & 15, kg = lane >> 4;
    float v; unsigned short* dst;
    if (T < 32) {                 // W_nbr [256][49], 16 ntiles x 2 ksteps, K pad 64
        int nt = T >> 1, ks = T & 1;
        int n = nt*16 + col16, k = ks*32 + kg*8 + j;
        v = (k < KN) ? Wnbr[n*KN + k] : 0.0f;
        dst = ws + (WS_WNBR>>1) + (size_t)T*512 + e;
    } else if (T < 160) {         // W_att [256][256], 16 x 8
        int T2 = T - 32;
        int nt = T2 >> 3, ks = T2 & 7;
        v = Watt[(nt*16 + col16)*F + ks*32 + kg*8 + j];
        dst = ws + (WS_WATT>>1) + (size_t)T2*512 + e;
    } else if (T < 544) {         // W_ih [768][256], 48 x 8
        int T3 = T - 160;
        int nt = T3 >> 3, ks = T3 & 7;
        v = Wih[(nt*16 + col16)*F + ks*32 + kg*8 + j];
        dst = ws + (WS_WIH>>1) + (size_t)T3*512 + e;
    } else {                      // W_hh [768][256], 48 x 8
        int T4 = T - 544;
        int nt = T4 >> 3, ks = T4 & 7;
        v = Whh[(nt*16 + col16)*F + ks*32 + kg*8 + j];
        dst = ws + (WS_WHH>>1) + (size_t)T4*512 + e;
    }
    *dst = f2bf(v);
}

// ---------------- K1: atom_feature (f32 VALU) + ascore ----------------
__global__ __launch_bounds__(NT)
void k1_atomfeat(const float* __restrict__ atom, const float* __restrict__ Watom,
                 const float* __restrict__ batom, const float* __restrict__ Walign,
                 unsigned short* __restrict__ af_bf, float* __restrict__ ascore_g)
{
    __shared__ float wl[256*41];      // W_atom, padded stride 41 (bank-free per-lane rows)
    __shared__ float arow[TB][AD];
    __shared__ float part[4][TB];
    const int t = threadIdx.x;
    const int g0 = blockIdx.x*TB;
    for (int i = t; i < 256*AD; i += NT) wl[(i/AD)*41 + (i%AD)] = Watom[i];
    for (int i = t; i < TB*AD; i += NT) arow[i/AD][i%AD] = atom[(size_t)g0*AD + i];
    __syncthreads();
    const float bb  = batom[t];
    const float wal = Walign[t];      // first 256 = atom-part of W_align
    const int w = t >> 6;
    const int lane = t & 63;
    for (int a = 0; a < TB; ++a) {
        float acc = bb;
        #pragma unroll
        for (int d = 0; d < AD; ++d) acc += arow[a][d]*wl[t*41 + d];
        float v = lrelu(acc);
        af_bf[(size_t)(g0+a)*F + t] = f2bf(v);
        float ps = v*wal;
        ps += __shfl_xor(ps, 1);  ps += __shfl_xor(ps, 2);
        ps += __shfl_xor(ps, 4);  ps += __shfl_xor(ps, 8);
        ps += __shfl_xor(ps, 16); ps += __shfl_xor(ps, 32);
        if (lane == 0) part[w][a] = ps;
    }
    __syncthreads();
    if (t < TB) ascore_g[g0 + t] = part[0][t] + part[1][t] + part[2][t] + part[3][t];
}

// ---------------- K2: neighbor MFMA + softmax + wn ----------------
#define ANP 72    // padded A_nbr row (ushorts)
#define NFP 264   // padded nf row (ushorts)
__global__ __launch_bounds__(NT)
void k2_neighbor(const float* __restrict__ atom, const float* __restrict__ bond,
                 const int* __restrict__ adeg_g, const int* __restrict__ bdeg_g,
                 const float* __restrict__ Walign, const float* __restrict__ balign,
                 const float* __restrict__ bnbr, const float* __restrict__ ascore_g,
                 const unsigned short* __restrict__ ws,
                 unsigned short* __restrict__ wn_g, float* __restrict__ sumaw_g)
{
    __shared__ unsigned short an[NR*ANP];   // 13824 B
    __shared__ unsigned short nfl[NR*NFP];  // 50688 B
    __shared__ float nscore[NR];
    __shared__ float awl[NR];
    __shared__ int adeg[NR], bdeg[NR];
    const int t = threadIdx.x;
    const int g0 = blockIdx.x*TB;
    const int molbase = (g0/Lm)*Lm;
    if (t < NR) {
        adeg[t] = adeg_g[(size_t)g0*Mn + t];
        bdeg[t] = bdeg_g[(size_t)g0*Mn + t];
        nscore[t] = 0.f;
    }
    __syncthreads();
    // gather neighbors -> bf16 LDS, K zero-padded to 64
    for (int i = t; i < NR*KNP; i += NT) {
        int r = i >> 6, d = i & 63;
        float v = 0.f;
        if (d < AD)      v = atom[(size_t)(molbase + adeg[r])*AD + d];
        else if (d < KN) v = bond[(size_t)(molbase + bdeg[r])*BDm + (d-AD)];
        an[r*ANP + d] = f2bf(v);
    }
    __syncthreads();
    // nf = lrelu(an @ Wnbr^T + b), MFMA; fused nscore partial reduce
    const int w = t >> 6, lane = t & 63;
    const int col16 = lane & 15, kg = lane >> 4;
    for (int i = 0; i < 24; ++i) {
        int T = w*24 + i;
        int mt = T >> 4, nt = T & 15;
        f32x4 acc = {0.f,0.f,0.f,0.f};
        #pragma unroll
        for (int ks = 0; ks < 2; ++ks) {
            bf16x8 a = *(const bf16x8*)&an[(mt*16 + col16)*ANP + ks*32 + kg*8];
            bf16x8 b = *(const bf16x8*)&ws[(WS_WNBR>>1) + (size_t)(nt*2 + ks)*512 + lane*8];
            acc = __builtin_amdgcn_mfma_f32_16x16x32_bf16(a, b, acc, 0, 0, 0);
        }
        const float bnb  = bnbr[nt*16 + col16];
        const float wal2 = Walign[F + nt*16 + col16];
        #pragma unroll
        for (int jj = 0; jj < 4; ++jj) {
            float v = lrelu(acc[jj] + bnb);
            int row = mt*16 + kg*4 + jj;
            nfl[row*NFP + nt*16 + col16] = f2bf(v);
            float ps = v*wal2;             // partial nscore: reduce over 16 cols
            ps += __shfl_xor(ps, 1); ps += __shfl_xor(ps, 2);
            ps += __shfl_xor(ps, 4); ps += __shfl_xor(ps, 8);
            if (col16 == 0) atomicAdd(&nscore[row], ps);
        }
    }
    __syncthreads();
    // masked softmax over m per atom
    if (t < TB) {
        const float ba = balign[0];
        const float as = ascore_g[g0 + t];
        float sc[Mn], msk[Mn];
        float mx = -1e30f;
        #pragma unroll
        for (int m = 0; m < Mn; ++m) {
            int pad = (adeg[t*Mn+m] == Lm-1);
            float s = lrelu(as + nscore[t*Mn+m] + ba) + (pad ? -9e8f : 0.0f);
            msk[m] = pad ? 0.f : 1.f;
            sc[m] = s; mx = fmaxf(mx, s);
        }
        float sum = 0.f;
        #pragma unroll
        for (int m = 0; m < Mn; ++m) { sc[m] = expf(sc[m]-mx); sum += sc[m]; }
        const float inv = 1.0f/sum;
        float sa = 0.f;
        #pragma unroll
        for (int m = 0; m < Mn; ++m) { float v = sc[m]*inv*msk[m]; awl[t*Mn+m] = v; sa += v; }
        sumaw_g[g0 + t] = sa;
    }
    __syncthreads();
    // wn[a][k=t] = sum_m aw * nf   -> global bf16
    for (int a = 0; a < TB; ++a) {
        float s = 0.f;
        #pragma unroll
        for (int m = 0; m < Mn; ++m)
            s += awl[a*Mn+m] * bf2f(nfl[(a*Mn+m)*NFP + t]);
        wn_g[(size_t)(g0+a)*F + t] = f2bf(s);
    }
}

// ---------------- K4: ctx GEMM (fused) + 6-way GRU GEMM + gates ----------------
__global__ __launch_bounds__(NT)
void k4_gru(const unsigned short* __restrict__ ws,
            const unsigned short* __restrict__ wn_g,
            const unsigned short* __restrict__ af_g,
            const float* __restrict__ sumaw_g, const float* __restrict__ batt,
            const float* __restrict__ bih, const float* __restrict__ bhh,
            float* __restrict__ out)
{
    __shared__ unsigned short ctxl[TB*NFP];   // 8448 B
    __shared__ float sumawl[TB];
    const int t = threadIdx.x;
    const int g0 = blockIdx.x*TB;
    if (t < TB) sumawl[t] = sumaw_g[g0 + t];
    __syncthreads();
    const int w = t >> 6, lane = t & 63;
    const int col16 = lane & 15, kg = lane >> 4;
    const unsigned short* wsAtt = ws + (WS_WATT>>1);
    const unsigned short* wsIh  = ws + (WS_WIH>>1);
    const unsigned short* wsHh  = ws + (WS_WHH>>1);
    // phase 1: ctx[16][w-slice 64] = elu(wn @ Watt^T + b_att*sumaw)
    {
        f32x4 acc[4];
        #pragma unroll
        for (int q = 0; q < 4; ++q) {
            float bb = batt[(w*4+q)*16 + col16];
            #pragma unroll
            for (int jj = 0; jj < 4; ++jj) acc[q][jj] = bb*sumawl[kg*4+jj];
        }
        for (int ks = 0; ks < 8; ++ks) {
            bf16x8 a = *(const bf16x8*)&wn_g[(size_t)(g0 + col16)*F + ks*32 + kg*8];
            #pragma unroll
            for (int q = 0; q < 4; ++q) {
                bf16x8 b = *(const bf16x8*)&wsAtt[(size_t)((w*4+q)*8 + ks)*512 + lane*8];
                acc[q] = __builtin_amdgcn_mfma_f32_16x16x32_bf16(a, b, acc[q], 0, 0, 0);
            }
        }
        #pragma unroll
        for (int q = 0; q < 4; ++q) {
            #pragma unroll
            for (int jj = 0; jj < 4; ++jj) {
                float x = acc[q][jj];
                x = (x > 0.f) ? x : expm1f(x);
                ctxl[(kg*4 + jj)*NFP + (w*4+q)*16 + col16] = f2bf(x);
            }
        }
    }
    __syncthreads();
    // phase 2: 6 gate GEMMs, K=256
    f32x4 acc[6][4];
    #pragma unroll
    for (int g = 0; g < 6; ++g) {
        const float* bias = (g < 3) ? bih : bhh;
        int gate = (g < 3) ? g : g-3;
        #pragma unroll
        for (int q = 0; q < 4; ++q) {
            float bb = bias[gate*F + w*64 + q*16 + col16];
            #pragma unroll
            for (int jj = 0; jj < 4; ++jj) acc[g][q][jj] = bb;
        }
    }
    for (int ks = 0; ks < 8; ++ks) {
        bf16x8 actx = *(const bf16x8*)&ctxl[col16*NFP + ks*32 + kg*8];
        bf16x8 aaf  = *(const bf16x8*)&af_g[(size_t)(g0 + col16)*F + ks*32 + kg*8];
        #pragma unroll
        for (int g = 0; g < 6; ++g) {
            const unsigned short* mat = (g < 3) ? wsIh : wsHh;
            int gate = (g < 3) ? g : g-3;
            bf16x8 aa = (g < 3) ? actx : aaf;
            #pragma unroll
            for (int q = 0; q < 4; ++q) {
                int nt = gate*16 + w*4 + q;
                bf16x8 b = *(const bf16x8*)&mat[(size_t)(nt*8 + ks)*512 + lane*8];
                acc[g][q] = __builtin_amdgcn_mfma_f32_16x16x32_bf16(aa, b, acc[g][q], 0, 0, 0);
            }
        }
    }
    // epilogue: GRU gates + relu
    #pragma unroll
    for (int q = 0; q < 4; ++q) {
        int f = w*64 + q*16 + col16;
        #pragma unroll
        for (int jj = 0; jj < 4; ++jj) {
            int a = kg*4 + jj;
            float ir = acc[0][q][jj], iz = acc[1][q][jj], in_ = acc[2][q][jj];
            float hr = acc[3][q][jj], hz = acc[4][q][jj], hn = acc[5][q][jj];
            float r = sigm(ir + hr);
            float z = sigm(iz + hz);
            float n = tanhf(in_ + r*hn);
            float h = bf2f(af_g[(size_t)(g0+a)*F + f]);
            float o = (1.f - z)*n + z*h;
            out[(size_t)(g0+a)*F + f] = fmaxf(o, 0.f);
        }
    }
}

extern "C" void kernel_launch(void* const* d_in, const int* in_sizes, int n_in,
                              void* d_out, int out_size, void* d_ws, size_t ws_size,
                              hipStream_t stream) {
    const float* atom_list = (const float*)d_in[0];
    const float* bond_list = (const float*)d_in[1];
    const int*   adeg      = (const int*)  d_in[2];
    const int*   bdeg      = (const int*)  d_in[3];
    const float* W_atom  = (const float*)d_in[5];
    const float* b_atom  = (const float*)d_in[6];
    const float* W_nbr   = (const float*)d_in[7];
    const float* b_nbr   = (const float*)d_in[8];
    const float* W_align = (const float*)d_in[9];
    const float* b_align = (const float*)d_in[10];
    const float* W_att   = (const float*)d_in[11];
    const float* b_att   = (const float*)d_in[12];
    const float* W_ih    = (const float*)d_in[13];
    const float* b_ih    = (const float*)d_in[14];
    const float* W_hh    = (const float*)d_in[15];
    const float* b_hh    = (const float*)d_in[16];
    float* out = (float*)d_out;

    unsigned short* wsu   = (unsigned short*)d_ws;
    unsigned short* af_bf = (unsigned short*)((char*)d_ws + WS_AF);
    float* ascore         = (float*)((char*)d_ws + WS_ASC);
    float* sumaw          = (float*)((char*)d_ws + WS_SUM);
    unsigned short* wn    = (unsigned short*)((char*)d_ws + WS_WN);

    const int ntiles = (Bsz*Lm)/TB;   // 4096
    p0_prep<<<1856, NT, 0, stream>>>(W_nbr, W_att, W_ih, W_hh, wsu);
    k1_atomfeat<<<ntiles, NT, 0, stream>>>(atom_list, W_atom, b_atom, W_align, af_bf, ascore);
    k2_neighbor<<<ntiles, NT, 0, stream>>>(atom_list, bond_list, adeg, bdeg,
                                           W_align, b_align, b_nbr, ascore,
                                           wsu, wn, sumaw);
    k4_gru<<<ntiles, NT, 0, stream>>>(wsu, wn, af_bf, sumaw, b_att, b_ih, b_hh, out);
}

// Round 3
// 455.935 us; speedup vs baseline: 14.8464x; 1.4320x over previous
//
#include <hip/hip_runtime.h>
#include <math.h>

#define Bsz 512
#define Lm  128
#define Mn  6
#define AD  39
#define BDm 10
#define KN  49          // AD+BDm
#define KNP 64          // padded K for neighbor GEMM
#define F   256
#define TB  16
#define NR  96          // TB*Mn
#define NT  256

// ws byte offsets
#define WS_WNBR 0
#define WS_WATT 32768
#define WS_WIH  163840
#define WS_WHH  557056
#define WS_AF   950272
#define WS_ASC  34504704
#define WS_SUM  34766848
#define WS_WN   35028992

typedef __attribute__((ext_vector_type(8))) short bf16x8;
typedef __attribute__((ext_vector_type(4))) float f32x4;

__device__ __forceinline__ float lrelu(float x){ return x > 0.0f ? x : 0.01f*x; }
__device__ __forceinline__ float sigm(float x){ return 1.0f/(1.0f+expf(-x)); }
__device__ __forceinline__ unsigned short f2bf(float f){
    unsigned int u = __builtin_bit_cast(unsigned int, f);
    u += 0x7fffu + ((u>>16)&1u);
    return (unsigned short)(u>>16);
}
__device__ __forceinline__ float bf2f(unsigned short h){
    unsigned int u = ((unsigned int)h)<<16;
    return __builtin_bit_cast(float, u);
}

// ---------------- P0: weights -> bf16 fragment-major ----------------
__global__ __launch_bounds__(NT)
void p0_prep(const float* __restrict__ Wnbr, const float* __restrict__ Watt,
             const float* __restrict__ Wih,  const float* __restrict__ Whh,
             unsigned short* __restrict__ ws)
{
    int id = blockIdx.x*NT + threadIdx.x;
    if (id >= 928*512) return;
    int T = id >> 9, e = id & 511;
    int lane = e >> 3, j = e & 7;
    int col16 = lane & 15, kg = lane >> 4;
    float v; unsigned short* dst;
    if (T < 32) {                 // W_nbr [256][49], 16 nt x 2 ks, K pad 64
        int nt = T >> 1, ks = T & 1;
        int n = nt*16 + col16, k = ks*32 + kg*8 + j;
        v = (k < KN) ? Wnbr[n*KN + k] : 0.0f;
        dst = ws + (WS_WNBR>>1) + (size_t)T*512 + e;
    } else if (T < 160) {         // W_att [256][256], 16 x 8
        int T2 = T - 32;
        int nt = T2 >> 3, ks = T2 & 7;
        v = Watt[(nt*16 + col16)*F + ks*32 + kg*8 + j];
        dst = ws + (WS_WATT>>1) + (size_t)T2*512 + e;
    } else if (T < 544) {         // W_ih [768][256], 48 x 8
        int T3 = T - 160;
        int nt = T3 >> 3, ks = T3 & 7;
        v = Wih[(nt*16 + col16)*F + ks*32 + kg*8 + j];
        dst = ws + (WS_WIH>>1) + (size_t)T3*512 + e;
    } else {                      // W_hh [768][256], 48 x 8
        int T4 = T - 544;
        int nt = T4 >> 3, ks = T4 & 7;
        v = Whh[(nt*16 + col16)*F + ks*32 + kg*8 + j];
        dst = ws + (WS_WHH>>1) + (size_t)T4*512 + e;
    }
    *dst = f2bf(v);
}

// ---------------- K1: atom_feature (f32 VALU) + ascore, 64 atoms/block ----------------
#define K1A 64
__global__ __launch_bounds__(NT)
void k1_atomfeat(const float* __restrict__ atom, const float* __restrict__ Watom,
                 const float* __restrict__ batom, const float* __restrict__ Walign,
                 unsigned short* __restrict__ af_bf, float* __restrict__ ascore_g)
{
    __shared__ float wl[256*41];
    __shared__ float arow[K1A][AD];
    __shared__ float part[4][K1A];
    const int t = threadIdx.x;
    const int g0 = blockIdx.x*K1A;
    for (int i = t; i < 256*AD; i += NT) wl[(i/AD)*41 + (i%AD)] = Watom[i];
    for (int i = t; i < K1A*AD; i += NT) arow[i/AD][i%AD] = atom[(size_t)g0*AD + i];
    __syncthreads();
    const float bb  = batom[t];
    const float wal = Walign[t];
    const int w = t >> 6;
    const int lane = t & 63;
    for (int a = 0; a < K1A; ++a) {
        float acc = bb;
        #pragma unroll
        for (int d = 0; d < AD; ++d) acc += arow[a][d]*wl[t*41 + d];
        float v = lrelu(acc);
        af_bf[(size_t)(g0+a)*F + t] = f2bf(v);
        float ps = v*wal;
        ps += __shfl_xor(ps, 1);  ps += __shfl_xor(ps, 2);
        ps += __shfl_xor(ps, 4);  ps += __shfl_xor(ps, 8);
        ps += __shfl_xor(ps, 16); ps += __shfl_xor(ps, 32);
        if (lane == 0) part[w][a] = ps;
    }
    __syncthreads();
    for (int a = t; a < K1A; a += NT)
        ascore_g[g0 + a] = part[0][a] + part[1][a] + part[2][a] + part[3][a];
}

// ---------------- K2: neighbor MFMA + softmax + wn (B-frag reuse over 6 m-tiles) ----------------
#define ANP 72
#define NFP 264
__global__ __launch_bounds__(NT)
void k2_neighbor(const float* __restrict__ atom, const float* __restrict__ bond,
                 const int* __restrict__ adeg_g, const int* __restrict__ bdeg_g,
                 const float* __restrict__ Walign, const float* __restrict__ balign,
                 const float* __restrict__ bnbr, const float* __restrict__ ascore_g,
                 const unsigned short* __restrict__ ws,
                 unsigned short* __restrict__ wn_g, float* __restrict__ sumaw_g)
{
    __shared__ unsigned short an[NR*ANP];
    __shared__ unsigned short nfl[NR*NFP];
    __shared__ float nscore[NR];
    __shared__ float awl[NR];
    __shared__ int adeg[NR], bdeg[NR];
    const int t = threadIdx.x;
    const int g0 = blockIdx.x*TB;
    const int molbase = (g0/Lm)*Lm;
    if (t < NR) {
        adeg[t] = adeg_g[(size_t)g0*Mn + t];
        bdeg[t] = bdeg_g[(size_t)g0*Mn + t];
        nscore[t] = 0.f;
    }
    __syncthreads();
    for (int i = t; i < NR*KNP; i += NT) {
        int r = i >> 6, d = i & 63;
        float v = 0.f;
        if (d < AD)      v = atom[(size_t)(molbase + adeg[r])*AD + d];
        else if (d < KN) v = bond[(size_t)(molbase + bdeg[r])*BDm + (d-AD)];
        an[r*ANP + d] = f2bf(v);
    }
    __syncthreads();
    const int w = t >> 6, lane = t & 63;
    const int col16 = lane & 15, kg = lane >> 4;
    // wave w owns nt in {4w..4w+3}, loops all 6 m-tiles; B frags hoisted
    f32x4 acc[6][4];
    #pragma unroll
    for (int mt = 0; mt < 6; ++mt)
        #pragma unroll
        for (int j = 0; j < 4; ++j) acc[mt][j] = (f32x4){0.f,0.f,0.f,0.f};
    #pragma unroll
    for (int ks = 0; ks < 2; ++ks) {
        bf16x8 b[4];
        #pragma unroll
        for (int j = 0; j < 4; ++j)
            b[j] = *(const bf16x8*)&ws[(WS_WNBR>>1) + (size_t)((4*w+j)*2 + ks)*512 + lane*8];
        #pragma unroll
        for (int mt = 0; mt < 6; ++mt) {
            bf16x8 a = *(const bf16x8*)&an[(mt*16 + col16)*ANP + ks*32 + kg*8];
            #pragma unroll
            for (int j = 0; j < 4; ++j)
                acc[mt][j] = __builtin_amdgcn_mfma_f32_16x16x32_bf16(a, b[j], acc[mt][j], 0, 0, 0);
        }
    }
    #pragma unroll
    for (int mt = 0; mt < 6; ++mt) {
        #pragma unroll
        for (int j = 0; j < 4; ++j) {
            const int nt = 4*w + j;
            const float bnb  = bnbr[nt*16 + col16];
            const float wal2 = Walign[F + nt*16 + col16];
            #pragma unroll
            for (int jj = 0; jj < 4; ++jj) {
                float v = lrelu(acc[mt][j][jj] + bnb);
                int row = mt*16 + kg*4 + jj;
                nfl[row*NFP + nt*16 + col16] = f2bf(v);
                float ps = v*wal2;
                ps += __shfl_xor(ps, 1); ps += __shfl_xor(ps, 2);
                ps += __shfl_xor(ps, 4); ps += __shfl_xor(ps, 8);
                if (col16 == 0) atomicAdd(&nscore[row], ps);
            }
        }
    }
    __syncthreads();
    if (t < TB) {
        const float ba = balign[0];
        const float as = ascore_g[g0 + t];
        float sc[Mn], msk[Mn];
        float mx = -1e30f;
        #pragma unroll
        for (int m = 0; m < Mn; ++m) {
            int pad = (adeg[t*Mn+m] == Lm-1);
            float s = lrelu(as + nscore[t*Mn+m] + ba) + (pad ? -9e8f : 0.0f);
            msk[m] = pad ? 0.f : 1.f;
            sc[m] = s; mx = fmaxf(mx, s);
        }
        float sum = 0.f;
        #pragma unroll
        for (int m = 0; m < Mn; ++m) { sc[m] = expf(sc[m]-mx); sum += sc[m]; }
        const float inv = 1.0f/sum;
        float sa = 0.f;
        #pragma unroll
        for (int m = 0; m < Mn; ++m) { float v = sc[m]*inv*msk[m]; awl[t*Mn+m] = v; sa += v; }
        sumaw_g[g0 + t] = sa;
    }
    __syncthreads();
    for (int a = 0; a < TB; ++a) {
        float s = 0.f;
        #pragma unroll
        for (int m = 0; m < Mn; ++m)
            s += awl[a*Mn+m] * bf2f(nfl[(a*Mn+m)*NFP + t]);
        wn_g[(size_t)(g0+a)*F + t] = f2bf(s);
    }
}

// ---------------- K4: 64 atoms/block, 8 waves, 4-acc GRU trick ----------------
#define NTK4 512
#define K4A  64
#define P264 264
__global__ __launch_bounds__(NTK4)
void k4_gru(const unsigned short* __restrict__ ws,
            const unsigned short* __restrict__ wn_g,
            const unsigned short* __restrict__ af_g,
            const float* __restrict__ sumaw_g, const float* __restrict__ batt,
            const float* __restrict__ bih, const float* __restrict__ bhh,
            float* __restrict__ out)
{
    __shared__ alignas(16) unsigned short wnl[K4A*P264];
    __shared__ alignas(16) unsigned short afl[K4A*P264];
    __shared__ alignas(16) unsigned short ctxl[K4A*P264];
    __shared__ float sumawl[K4A];
    const int t = threadIdx.x;
    const int g0 = blockIdx.x*K4A;
    // stage wn, af: 64 rows x 256 bf16 each, 16B chunks
    for (int i = t; i < K4A*32*2; i += NTK4) {
        int m = i >> 11;              // 0: wn, 1: af
        int ii = i & 2047;
        int row = ii >> 5, c8 = (ii & 31)*8;
        const unsigned short* src = m ? af_g : wn_g;
        unsigned short* dst = m ? afl : wnl;
        *(uint4*)&dst[row*P264 + c8] = *(const uint4*)&src[(size_t)(g0+row)*F + c8];
    }
    if (t < K4A) sumawl[t] = sumaw_g[g0 + t];
    __syncthreads();

    const int w = t >> 6, lane = t & 63;
    const int col16 = lane & 15, kg = lane >> 4;
    const unsigned short* wsAtt = ws + (WS_WATT>>1);
    const unsigned short* wsIh  = ws + (WS_WIH>>1);
    const unsigned short* wsHh  = ws + (WS_WHH>>1);

    // ---- phase 1: ctx = elu(wn @ Watt^T + b_att*sumaw); wave w -> nt {2w, 2w+1}
    {
        f32x4 c0[4], c1[4];
        const float bb0 = batt[(2*w)*16 + col16];
        const float bb1 = batt[(2*w+1)*16 + col16];
        #pragma unroll
        for (int mt = 0; mt < 4; ++mt)
            #pragma unroll
            for (int jj = 0; jj < 4; ++jj) {
                float sa = sumawl[mt*16 + kg*4 + jj];
                c0[mt][jj] = bb0*sa; c1[mt][jj] = bb1*sa;
            }
        #pragma unroll
        for (int ks = 0; ks < 8; ++ks) {
            bf16x8 b0 = *(const bf16x8*)&wsAtt[(size_t)((2*w)*8 + ks)*512 + lane*8];
            bf16x8 b1 = *(const bf16x8*)&wsAtt[(size_t)((2*w+1)*8 + ks)*512 + lane*8];
            #pragma unroll
            for (int mt = 0; mt < 4; ++mt) {
                bf16x8 a = *(const bf16x8*)&wnl[(mt*16 + col16)*P264 + ks*32 + kg*8];
                c0[mt] = __builtin_amdgcn_mfma_f32_16x16x32_bf16(a, b0, c0[mt], 0, 0, 0);
                c1[mt] = __builtin_amdgcn_mfma_f32_16x16x32_bf16(a, b1, c1[mt], 0, 0, 0);
            }
        }
        #pragma unroll
        for (int mt = 0; mt < 4; ++mt)
            #pragma unroll
            for (int jj = 0; jj < 4; ++jj) {
                int row = mt*16 + kg*4 + jj;
                float x0 = c0[mt][jj]; x0 = (x0 > 0.f) ? x0 : expm1f(x0);
                float x1 = c1[mt][jj]; x1 = (x1 > 0.f) ? x1 : expm1f(x1);
                ctxl[row*P264 + (2*w)*16   + col16] = f2bf(x0);
                ctxl[row*P264 + (2*w+1)*16 + col16] = f2bf(x1);
            }
    }
    __syncthreads();

    // ---- phase 2: r = sig(X@[Wih_r|Whh_r]), z likewise, n = tanh(in + r*hn)
    // wave w -> feature slice w*32 .. w*32+31 (q=0,1), all 64 atoms (mt=0..3)
    f32x4 rA[2][4], zA[2][4], nA[2][4], hA[2][4];   // 128 VGPRs
    {
        float rb[2], zb[2], nb[2], hb[2];
        #pragma unroll
        for (int q = 0; q < 2; ++q) {
            int f = w*32 + q*16 + col16;
            rb[q] = bih[f]       + bhh[f];
            zb[q] = bih[F + f]   + bhh[F + f];
            nb[q] = bih[2*F + f];
            hb[q] = bhh[2*F + f];
        }
        #pragma unroll
        for (int q = 0; q < 2; ++q)
            #pragma unroll
            for (int mt = 0; mt < 4; ++mt)
                #pragma unroll
                for (int jj = 0; jj < 4; ++jj) {
                    rA[q][mt][jj] = rb[q]; zA[q][mt][jj] = zb[q];
                    nA[q][mt][jj] = nb[q]; hA[q][mt][jj] = hb[q];
                }
    }
    #pragma unroll
    for (int ks = 0; ks < 8; ++ks) {
        // ih half: A = ctx
        {
            bf16x8 br0 = *(const bf16x8*)&wsIh[(size_t)((0*16 + 2*w+0)*8 + ks)*512 + lane*8];
            bf16x8 br1 = *(const bf16x8*)&wsIh[(size_t)((0*16 + 2*w+1)*8 + ks)*512 + lane*8];
            bf16x8 bz0 = *(const bf16x8*)&wsIh[(size_t)((1*16 + 2*w+0)*8 + ks)*512 + lane*8];
            bf16x8 bz1 = *(const bf16x8*)&wsIh[(size_t)((1*16 + 2*w+1)*8 + ks)*512 + lane*8];
            bf16x8 bn0 = *(const bf16x8*)&wsIh[(size_t)((2*16 + 2*w+0)*8 + ks)*512 + lane*8];
            bf16x8 bn1 = *(const bf16x8*)&wsIh[(size_t)((2*16 + 2*w+1)*8 + ks)*512 + lane*8];
            #pragma unroll
            for (int mt = 0; mt < 4; ++mt) {
                bf16x8 a = *(const bf16x8*)&ctxl[(mt*16 + col16)*P264 + ks*32 + kg*8];
                rA[0][mt] = __builtin_amdgcn_mfma_f32_16x16x32_bf16(a, br0, rA[0][mt], 0, 0, 0);
                rA[1][mt] = __builtin_amdgcn_mfma_f32_16x16x32_bf16(a, br1, rA[1][mt], 0, 0, 0);
                zA[0][mt] = __builtin_amdgcn_mfma_f32_16x16x32_bf16(a, bz0, zA[0][mt], 0, 0, 0);
                zA[1][mt] = __builtin_amdgcn_mfma_f32_16x16x32_bf16(a, bz1, zA[1][mt], 0, 0, 0);
                nA[0][mt] = __builtin_amdgcn_mfma_f32_16x16x32_bf16(a, bn0, nA[0][mt], 0, 0, 0);
                nA[1][mt] = __builtin_amdgcn_mfma_f32_16x16x32_bf16(a, bn1, nA[1][mt], 0, 0, 0);
            }
        }
        // hh half: A = af
        {
            bf16x8 br0 = *(const bf16x8*)&wsHh[(size_t)((0*16 + 2*w+0)*8 + ks)*512 + lane*8];
            bf16x8 br1 = *(const bf16x8*)&wsHh[(size_t)((0*16 + 2*w+1)*8 + ks)*512 + lane*8];
            bf16x8 bz0 = *(const bf16x8*)&wsHh[(size_t)((1*16 + 2*w+0)*8 + ks)*512 + lane*8];
            bf16x8 bz1 = *(const bf16x8*)&wsHh[(size_t)((1*16 + 2*w+1)*8 + ks)*512 + lane*8];
            bf16x8 bh0 = *(const bf16x8*)&wsHh[(size_t)((2*16 + 2*w+0)*8 + ks)*512 + lane*8];
            bf16x8 bh1 = *(const bf16x8*)&wsHh[(size_t)((2*16 + 2*w+1)*8 + ks)*512 + lane*8];
            #pragma unroll
            for (int mt = 0; mt < 4; ++mt) {
                bf16x8 a = *(const bf16x8*)&afl[(mt*16 + col16)*P264 + ks*32 + kg*8];
                rA[0][mt] = __builtin_amdgcn_mfma_f32_16x16x32_bf16(a, br0, rA[0][mt], 0, 0, 0);
                rA[1][mt] = __builtin_amdgcn_mfma_f32_16x16x32_bf16(a, br1, rA[1][mt], 0, 0, 0);
                zA[0][mt] = __builtin_amdgcn_mfma_f32_16x16x32_bf16(a, bz0, zA[0][mt], 0, 0, 0);
                zA[1][mt] = __builtin_amdgcn_mfma_f32_16x16x32_bf16(a, bz1, zA[1][mt], 0, 0, 0);
                hA[0][mt] = __builtin_amdgcn_mfma_f32_16x16x32_bf16(a, bh0, hA[0][mt], 0, 0, 0);
                hA[1][mt] = __builtin_amdgcn_mfma_f32_16x16x32_bf16(a, bh1, hA[1][mt], 0, 0, 0);
            }
        }
    }
    // epilogue: GRU gates + relu
    #pragma unroll
    for (int q = 0; q < 2; ++q) {
        int f = w*32 + q*16 + col16;
        #pragma unroll
        for (int mt = 0; mt < 4; ++mt)
            #pragma unroll
            for (int jj = 0; jj < 4; ++jj) {
                int a = mt*16 + kg*4 + jj;
                float r = sigm(rA[q][mt][jj]);
                float z = sigm(zA[q][mt][jj]);
                float n = tanhf(nA[q][mt][jj] + r*hA[q][mt][jj]);
                float h = bf2f(afl[a*P264 + f]);
                float o = (1.f - z)*n + z*h;
                out[(size_t)(g0+a)*F + f] = fmaxf(o, 0.f);
            }
    }
}

extern "C" void kernel_launch(void* const* d_in, const int* in_sizes, int n_in,
                              void* d_out, int out_size, void* d_ws, size_t ws_size,
                              hipStream_t stream) {
    const float* atom_list = (const float*)d_in[0];
    const float* bond_list = (const float*)d_in[1];
    const int*   adeg      = (const int*)  d_in[2];
    const int*   bdeg      = (const int*)  d_in[3];
    const float* W_atom  = (const float*)d_in[5];
    const float* b_atom  = (const float*)d_in[6];
    const float* W_nbr   = (const float*)d_in[7];
    const float* b_nbr   = (const float*)d_in[8];
    const float* W_align = (const float*)d_in[9];
    const float* b_align = (const float*)d_in[10];
    const float* W_att   = (const float*)d_in[11];
    const float* b_att   = (const float*)d_in[12];
    const float* W_ih    = (const float*)d_in[13];
    const float* b_ih    = (const float*)d_in[14];
    const float* W_hh    = (const float*)d_in[15];
    const float* b_hh    = (const float*)d_in[16];
    float* out = (float*)d_out;

    unsigned short* wsu   = (unsigned short*)d_ws;
    unsigned short* af_bf = (unsigned short*)((char*)d_ws + WS_AF);
    float* ascore         = (float*)((char*)d_ws + WS_ASC);
    float* sumaw          = (float*)((char*)d_ws + WS_SUM);
    unsigned short* wn    = (unsigned short*)((char*)d_ws + WS_WN);

    p0_prep<<<1856, NT, 0, stream>>>(W_nbr, W_att, W_ih, W_hh, wsu);
    k1_atomfeat<<<(Bsz*Lm)/K1A, NT, 0, stream>>>(atom_list, W_atom, b_atom, W_align, af_bf, ascore);
    k2_neighbor<<<(Bsz*Lm)/TB, NT, 0, stream>>>(atom_list, bond_list, adeg, bdeg,
                                                W_align, b_align, b_nbr, ascore,
                                                wsu, wn, sumaw);
    k4_gru<<<(Bsz*Lm)/K4A, NTK4, 0, stream>>>(wsu, wn, af_bf, sumaw, b_att, b_ih, b_hh, out);
}

// Round 4
// 289.181 us; speedup vs baseline: 23.4074x; 1.5766x over previous
//
#include <hip/hip_runtime.h>
#include <math.h>

#define Bsz 512
#define Lm  128
#define Mn  6
#define AD  39
#define BDm 10
#define KN  49          // AD+BDm
#define F   256
#define TB  16
#define NR  96          // TB*Mn
#define NFP 264         // padded nf/af/wn/ctx row stride (ushorts)
#define ANP 72          // padded A-row stride (ushorts), K padded to 64

// ws byte offsets
#define WS_WATM 0
#define WS_WNBR 32768
#define WS_WATT 65536
#define WS_WIH  196608
#define WS_WHH  589824
#define WS_SUM  983040
#define WS_WN   1245184
// end: 34799616 bytes (~33.2 MB)

typedef __attribute__((ext_vector_type(8))) short bf16x8;
typedef __attribute__((ext_vector_type(4))) float f32x4;

__device__ __forceinline__ float lrelu(float x){ return x > 0.0f ? x : 0.01f*x; }
__device__ __forceinline__ float sigm(float x){ return 1.0f/(1.0f+expf(-x)); }
__device__ __forceinline__ unsigned short f2bf(float f){
    unsigned int u = __builtin_bit_cast(unsigned int, f);
    u += 0x7fffu + ((u>>16)&1u);
    return (unsigned short)(u>>16);
}
__device__ __forceinline__ float bf2f(unsigned short h){
    unsigned int u = ((unsigned int)h)<<16;
    return __builtin_bit_cast(float, u);
}

// ---------------- P0: weights -> bf16 fragment-major ----------------
// frag: elem e = lane*8+j; n = nt*16+(lane&15); k = ks*32+(lane>>4)*8+j
__global__ __launch_bounds__(256)
void p0_prep(const float* __restrict__ Watm, const float* __restrict__ Wnbr,
             const float* __restrict__ Watt, const float* __restrict__ Wih,
             const float* __restrict__ Whh,  unsigned short* __restrict__ ws)
{
    int id = blockIdx.x*256 + threadIdx.x;
    if (id >= 960*512) return;
    int T = id >> 9, e = id & 511;
    int lane = e >> 3, j = e & 7;
    int col16 = lane & 15, kg = lane >> 4;
    float v; unsigned short* dst;
    if (T < 32) {                 // W_atom [256][39], 16 nt x 2 ks, K pad 64
        int nt = T >> 1, ks = T & 1;
        int k = ks*32 + kg*8 + j;
        v = (k < AD) ? Watm[(nt*16 + col16)*AD + k] : 0.0f;
        dst = ws + (WS_WATM>>1) + (size_t)T*512 + e;
    } else if (T < 64) {          // W_nbr [256][49], pad 64
        int T2 = T - 32;
        int nt = T2 >> 1, ks = T2 & 1;
        int k = ks*32 + kg*8 + j;
        v = (k < KN) ? Wnbr[(nt*16 + col16)*KN + k] : 0.0f;
        dst = ws + (WS_WNBR>>1) + (size_t)T2*512 + e;
    } else if (T < 192) {         // W_att [256][256], 16 x 8
        int T2 = T - 64;
        int nt = T2 >> 3, ks = T2 & 7;
        v = Watt[(nt*16 + col16)*F + ks*32 + kg*8 + j];
        dst = ws + (WS_WATT>>1) + (size_t)T2*512 + e;
    } else if (T < 576) {         // W_ih [768][256], 48 x 8
        int T3 = T - 192;
        int nt = T3 >> 3, ks = T3 & 7;
        v = Wih[(nt*16 + col16)*F + ks*32 + kg*8 + j];
        dst = ws + (WS_WIH>>1) + (size_t)T3*512 + e;
    } else {                      // W_hh [768][256], 48 x 8
        int T4 = T - 576;
        int nt = T4 >> 3, ks = T4 & 7;
        v = Whh[(nt*16 + col16)*F + ks*32 + kg*8 + j];
        dst = ws + (WS_WHH>>1) + (size_t)T4*512 + e;
    }
    *dst = f2bf(v);
}

// ---------------- K2: atom-score MFMA + neighbor MFMA + softmax + wn ----------------
#define NT2 256
__global__ __launch_bounds__(NT2, 3)
void k2_nbr(const float* __restrict__ atom, const float* __restrict__ bond,
            const int* __restrict__ adeg_g, const int* __restrict__ bdeg_g,
            const float* __restrict__ Walign, const float* __restrict__ balign,
            const float* __restrict__ batom,  const float* __restrict__ bnbr,
            const unsigned short* __restrict__ ws,
            unsigned short* __restrict__ wn_g, float* __restrict__ sumaw_g)
{
    __shared__ alignas(16) unsigned short nfl[NR*NFP];   // 50688 B; staging overlaid below
    __shared__ float ascl[TB];
    __shared__ float nscl[NR];
    __shared__ float awl[NR];
    __shared__ int   adeg[NR];
    unsigned short* arowl = nfl;            // [16][72] overlay (dead before nfl writes)
    unsigned short* anl   = nfl + TB*ANP;   // [96][72] overlay

    const int t  = threadIdx.x;
    const int g0 = blockIdx.x*TB;
    const int molbase = (g0/Lm)*Lm;

    if (t < NR) { adeg[t] = adeg_g[(size_t)g0*Mn + t]; nscl[t] = 0.f; }
    if (t < TB) ascl[t] = 0.f;
    __syncthreads();   // B0: adeg + zeroed accumulators visible

    // stage own rows (pad K 39->64) and neighbor gathers (pad 49->64)
    for (int i = t; i < TB*64; i += NT2) {
        int r = i >> 6, d = i & 63;
        float v = (d < AD) ? atom[(size_t)(g0+r)*AD + d] : 0.f;
        arowl[r*ANP + d] = f2bf(v);
    }
    for (int i = t; i < NR*64; i += NT2) {
        int r = i >> 6, d = i & 63;
        float v = 0.f;
        if (d < AD)      v = atom[(size_t)(molbase + adeg[r])*AD + d];
        else if (d < KN) v = bond[(size_t)(molbase + bdeg_g[(size_t)g0*Mn + r])*BDm + (d-AD)];
        anl[r*ANP + d] = f2bf(v);
    }
    __syncthreads();   // B1: staging visible

    const int w = t >> 6, lane = t & 63;
    const int col16 = lane & 15, kg = lane >> 4;

    // ---- atom MFMA -> ascore only (af recomputed in k4)
    {
        f32x4 acc[4];
        #pragma unroll
        for (int j = 0; j < 4; ++j) acc[j] = (f32x4){0.f,0.f,0.f,0.f};
        #pragma unroll
        for (int ks = 0; ks < 2; ++ks) {
            bf16x8 a = *(const bf16x8*)&arowl[col16*ANP + ks*32 + kg*8];
            #pragma unroll
            for (int j = 0; j < 4; ++j) {
                bf16x8 b = *(const bf16x8*)&ws[(WS_WATM>>1) + (size_t)((4*w+j)*2 + ks)*512 + lane*8];
                acc[j] = __builtin_amdgcn_mfma_f32_16x16x32_bf16(a, b, acc[j], 0, 0, 0);
            }
        }
        float ps[4] = {0.f,0.f,0.f,0.f};
        #pragma unroll
        for (int j = 0; j < 4; ++j) {
            const int col = (4*w+j)*16 + col16;
            const float bb  = batom[col];
            const float wal = Walign[col];
            #pragma unroll
            for (int jj = 0; jj < 4; ++jj) ps[jj] += lrelu(acc[j][jj] + bb)*wal;
        }
        #pragma unroll
        for (int jj = 0; jj < 4; ++jj) {
            float p = ps[jj];
            p += __shfl_xor(p, 1); p += __shfl_xor(p, 2);
            p += __shfl_xor(p, 4); p += __shfl_xor(p, 8);
            if (col16 == 0) atomicAdd(&ascl[kg*4 + jj], p);
        }
    }

    // ---- neighbor MFMA (acc in regs across barrier)
    f32x4 acc[6][4];
    #pragma unroll
    for (int mt = 0; mt < 6; ++mt)
        #pragma unroll
        for (int j = 0; j < 4; ++j) acc[mt][j] = (f32x4){0.f,0.f,0.f,0.f};
    #pragma unroll
    for (int ks = 0; ks < 2; ++ks) {
        bf16x8 b[4];
        #pragma unroll
        for (int j = 0; j < 4; ++j)
            b[j] = *(const bf16x8*)&ws[(WS_WNBR>>1) + (size_t)((4*w+j)*2 + ks)*512 + lane*8];
        #pragma unroll
        for (int mt = 0; mt < 6; ++mt) {
            bf16x8 a = *(const bf16x8*)&anl[(mt*16 + col16)*ANP + ks*32 + kg*8];
            #pragma unroll
            for (int j = 0; j < 4; ++j)
                acc[mt][j] = __builtin_amdgcn_mfma_f32_16x16x32_bf16(a, b[j], acc[mt][j], 0, 0, 0);
        }
    }
    __syncthreads();   // B2: all arowl/anl reads done -> nfl writes safe

    // epilogue: nf -> LDS (bf16), nscore partials
    #pragma unroll
    for (int mt = 0; mt < 6; ++mt) {
        float pns[4] = {0.f,0.f,0.f,0.f};
        #pragma unroll
        for (int j = 0; j < 4; ++j) {
            const int col = (4*w+j)*16 + col16;
            const float bnb  = bnbr[col];
            const float wal2 = Walign[F + col];
            #pragma unroll
            for (int jj = 0; jj < 4; ++jj) {
                float v = lrelu(acc[mt][j][jj] + bnb);
                nfl[(mt*16 + kg*4 + jj)*NFP + col] = f2bf(v);
                pns[jj] += v*wal2;
            }
        }
        #pragma unroll
        for (int jj = 0; jj < 4; ++jj) {
            float p = pns[jj];
            p += __shfl_xor(p, 1); p += __shfl_xor(p, 2);
            p += __shfl_xor(p, 4); p += __shfl_xor(p, 8);
            if (col16 == 0) atomicAdd(&nscl[mt*16 + kg*4 + jj], p);
        }
    }
    __syncthreads();   // B3: nfl + nscl complete

    if (t < TB) {
        const float ba = balign[0];
        const float as = ascl[t];
        float sc[Mn], msk[Mn];
        float mx = -1e30f;
        #pragma unroll
        for (int m = 0; m < Mn; ++m) {
            int pad = (adeg[t*Mn+m] == Lm-1);
            float s = lrelu(as + nscl[t*Mn+m] + ba) + (pad ? -9e8f : 0.0f);
            msk[m] = pad ? 0.f : 1.f;
            sc[m] = s; mx = fmaxf(mx, s);
        }
        float sum = 0.f;
        #pragma unroll
        for (int m = 0; m < Mn; ++m) { sc[m] = expf(sc[m]-mx); sum += sc[m]; }
        const float inv = 1.0f/sum;
        float sa = 0.f;
        #pragma unroll
        for (int m = 0; m < Mn; ++m) { float v = sc[m]*inv*msk[m]; awl[t*Mn+m] = v; sa += v; }
        sumaw_g[g0 + t] = sa;
    }
    __syncthreads();   // B4: awl visible

    // wn[a][:] = sum_m aw*nf  -- vectorized b128 reads, packed stores
    #pragma unroll
    for (int rep = 0; rep < 2; ++rep) {
        const int idx = t + rep*NT2;
        const int a = idx & 15, cg = idx >> 4;     // cg in [0,32)
        float o[8] = {0,0,0,0,0,0,0,0};
        #pragma unroll
        for (int m = 0; m < Mn; ++m) {
            const float aw = awl[a*Mn + m];
            uint4 v = *(const uint4*)&nfl[(a*Mn+m)*NFP + cg*8];
            unsigned int d0 = v.x, d1 = v.y, d2 = v.z, d3 = v.w;
            o[0] += aw*__builtin_bit_cast(float, d0<<16);
            o[1] += aw*__builtin_bit_cast(float, d0 & 0xffff0000u);
            o[2] += aw*__builtin_bit_cast(float, d1<<16);
            o[3] += aw*__builtin_bit_cast(float, d1 & 0xffff0000u);
            o[4] += aw*__builtin_bit_cast(float, d2<<16);
            o[5] += aw*__builtin_bit_cast(float, d2 & 0xffff0000u);
            o[6] += aw*__builtin_bit_cast(float, d3<<16);
            o[7] += aw*__builtin_bit_cast(float, d3 & 0xffff0000u);
        }
        uint4 pv;
        pv.x = (unsigned int)f2bf(o[0]) | ((unsigned int)f2bf(o[1])<<16);
        pv.y = (unsigned int)f2bf(o[2]) | ((unsigned int)f2bf(o[3])<<16);
        pv.z = (unsigned int)f2bf(o[4]) | ((unsigned int)f2bf(o[5])<<16);
        pv.w = (unsigned int)f2bf(o[6]) | ((unsigned int)f2bf(o[7])<<16);
        *(uint4*)&wn_g[(size_t)(g0+a)*F + cg*8] = pv;
    }
}

// ---------------- K4: af MFMA + ctx GEMM + 6-way GRU GEMM + gates ----------------
#define NTK4 512
#define K4A  64
__global__ __launch_bounds__(NTK4)
void k4_gru(const unsigned short* __restrict__ ws,
            const unsigned short* __restrict__ wn_g,
            const float* __restrict__ atom,
            const float* __restrict__ sumaw_g, const float* __restrict__ batom,
            const float* __restrict__ batt,
            const float* __restrict__ bih, const float* __restrict__ bhh,
            float* __restrict__ out)
{
    __shared__ alignas(16) unsigned short wnl[K4A*NFP];   // 33792 B; ctxl overlays after phase1
    __shared__ alignas(16) unsigned short afl[K4A*NFP];   // 33792 B
    __shared__ alignas(16) unsigned short arowl[K4A*ANP]; // 9216 B
    __shared__ float sumawl[K4A];
    const int t  = threadIdx.x;
    const int g0 = blockIdx.x*K4A;

    for (int i = t; i < K4A*32; i += NTK4) {
        int row = i >> 5, cg = i & 31;
        *(uint4*)&wnl[row*NFP + cg*8] = *(const uint4*)&wn_g[(size_t)(g0+row)*F + cg*8];
    }
    for (int i = t; i < K4A*64; i += NTK4) {
        int r = i >> 6, d = i & 63;
        float v = (d < AD) ? atom[(size_t)(g0+r)*AD + d] : 0.f;
        arowl[r*ANP + d] = f2bf(v);
    }
    if (t < K4A) sumawl[t] = sumaw_g[g0 + t];
    __syncthreads();   // B1

    const int w = t >> 6, lane = t & 63;
    const int col16 = lane & 15, kg = lane >> 4;
    const unsigned short* wsAtm = ws + (WS_WATM>>1);
    const unsigned short* wsAtt = ws + (WS_WATT>>1);
    const unsigned short* wsIh  = ws + (WS_WIH>>1);
    const unsigned short* wsHh  = ws + (WS_WHH>>1);

    // ---- phase 0: af = lrelu(arow @ Watom^T + b); wave w -> nt {2w, 2w+1}
    {
        f32x4 a0[4], a1[4];
        #pragma unroll
        for (int mt = 0; mt < 4; ++mt) { a0[mt] = (f32x4){0,0,0,0}; a1[mt] = (f32x4){0,0,0,0}; }
        #pragma unroll
        for (int ks = 0; ks < 2; ++ks) {
            bf16x8 b0 = *(const bf16x8*)&wsAtm[(size_t)((2*w)*2   + ks)*512 + lane*8];
            bf16x8 b1 = *(const bf16x8*)&wsAtm[(size_t)((2*w+1)*2 + ks)*512 + lane*8];
            #pragma unroll
            for (int mt = 0; mt < 4; ++mt) {
                bf16x8 a = *(const bf16x8*)&arowl[(mt*16 + col16)*ANP + ks*32 + kg*8];
                a0[mt] = __builtin_amdgcn_mfma_f32_16x16x32_bf16(a, b0, a0[mt], 0, 0, 0);
                a1[mt] = __builtin_amdgcn_mfma_f32_16x16x32_bf16(a, b1, a1[mt], 0, 0, 0);
            }
        }
        const float bb0 = batom[(2*w)*16   + col16];
        const float bb1 = batom[(2*w+1)*16 + col16];
        #pragma unroll
        for (int mt = 0; mt < 4; ++mt)
            #pragma unroll
            for (int jj = 0; jj < 4; ++jj) {
                int row = mt*16 + kg*4 + jj;
                afl[row*NFP + (2*w)*16   + col16] = f2bf(lrelu(a0[mt][jj] + bb0));
                afl[row*NFP + (2*w+1)*16 + col16] = f2bf(lrelu(a1[mt][jj] + bb1));
            }
    }

    // ---- phase 1: ctx = elu(wn @ Watt^T + b_att*sumaw); wave w -> nt {2w, 2w+1}
    f32x4 c0[4], c1[4];
    {
        const float bb0 = batt[(2*w)*16   + col16];
        const float bb1 = batt[(2*w+1)*16 + col16];
        #pragma unroll
        for (int mt = 0; mt < 4; ++mt)
            #pragma unroll
            for (int jj = 0; jj < 4; ++jj) {
                float sa = sumawl[mt*16 + kg*4 + jj];
                c0[mt][jj] = bb0*sa; c1[mt][jj] = bb1*sa;
            }
        #pragma unroll
        for (int ks = 0; ks < 8; ++ks) {
            bf16x8 b0 = *(const bf16x8*)&wsAtt[(size_t)((2*w)*8   + ks)*512 + lane*8];
            bf16x8 b1 = *(const bf16x8*)&wsAtt[(size_t)((2*w+1)*8 + ks)*512 + lane*8];
            #pragma unroll
            for (int mt = 0; mt < 4; ++mt) {
                bf16x8 a = *(const bf16x8*)&wnl[(mt*16 + col16)*NFP + ks*32 + kg*8];
                c0[mt] = __builtin_amdgcn_mfma_f32_16x16x32_bf16(a, b0, c0[mt], 0, 0, 0);
                c1[mt] = __builtin_amdgcn_mfma_f32_16x16x32_bf16(a, b1, c1[mt], 0, 0, 0);
            }
        }
    }
    __syncthreads();   // B2: all wnl reads done -> ctx overlay safe
    unsigned short* ctxl = wnl;
    #pragma unroll
    for (int mt = 0; mt < 4; ++mt)
        #pragma unroll
        for (int jj = 0; jj < 4; ++jj) {
            int row = mt*16 + kg*4 + jj;
            float x0 = c0[mt][jj]; x0 = (x0 > 0.f) ? x0 : expm1f(x0);
            float x1 = c1[mt][jj]; x1 = (x1 > 0.f) ? x1 : expm1f(x1);
            ctxl[row*NFP + (2*w)*16   + col16] = f2bf(x0);
            ctxl[row*NFP + (2*w+1)*16 + col16] = f2bf(x1);
        }
    __syncthreads();   // B3: ctxl visible

    // ---- phase 2: GRU gate GEMMs; wave w -> feature slice w*32..w*32+31
    f32x4 rA[2][4], zA[2][4], nA[2][4], hA[2][4];
    {
        float rb[2], zb[2], nb[2], hb[2];
        #pragma unroll
        for (int q = 0; q < 2; ++q) {
            int f = w*32 + q*16 + col16;
            rb[q] = bih[f]       + bhh[f];
            zb[q] = bih[F + f]   + bhh[F + f];
            nb[q] = bih[2*F + f];
            hb[q] = bhh[2*F + f];
        }
        #pragma unroll
        for (int q = 0; q < 2; ++q)
            #pragma unroll
            for (int mt = 0; mt < 4; ++mt)
                #pragma unroll
                for (int jj = 0; jj < 4; ++jj) {
                    rA[q][mt][jj] = rb[q]; zA[q][mt][jj] = zb[q];
                    nA[q][mt][jj] = nb[q]; hA[q][mt][jj] = hb[q];
                }
    }
    #pragma unroll
    for (int ks = 0; ks < 8; ++ks) {
        {
            bf16x8 br0 = *(const bf16x8*)&wsIh[(size_t)((0*16 + 2*w+0)*8 + ks)*512 + lane*8];
            bf16x8 br1 = *(const bf16x8*)&wsIh[(size_t)((0*16 + 2*w+1)*8 + ks)*512 + lane*8];
            bf16x8 bz0 = *(const bf16x8*)&wsIh[(size_t)((1*16 + 2*w+0)*8 + ks)*512 + lane*8];
            bf16x8 bz1 = *(const bf16x8*)&wsIh[(size_t)((1*16 + 2*w+1)*8 + ks)*512 + lane*8];
            bf16x8 bn0 = *(const bf16x8*)&wsIh[(size_t)((2*16 + 2*w+0)*8 + ks)*512 + lane*8];
            bf16x8 bn1 = *(const bf16x8*)&wsIh[(size_t)((2*16 + 2*w+1)*8 + ks)*512 + lane*8];
            #pragma unroll
            for (int mt = 0; mt < 4; ++mt) {
                bf16x8 a = *(const bf16x8*)&ctxl[(mt*16 + col16)*NFP + ks*32 + kg*8];
                rA[0][mt] = __builtin_amdgcn_mfma_f32_16x16x32_bf16(a, br0, rA[0][mt], 0, 0, 0);
                rA[1][mt] = __builtin_amdgcn_mfma_f32_16x16x32_bf16(a, br1, rA[1][mt], 0, 0, 0);
                zA[0][mt] = __builtin_amdgcn_mfma_f32_16x16x32_bf16(a, bz0, zA[0][mt], 0, 0, 0);
                zA[1][mt] = __builtin_amdgcn_mfma_f32_16x16x32_bf16(a, bz1, zA[1][mt], 0, 0, 0);
                nA[0][mt] = __builtin_amdgcn_mfma_f32_16x16x32_bf16(a, bn0, nA[0][mt], 0, 0, 0);
                nA[1][mt] = __builtin_amdgcn_mfma_f32_16x16x32_bf16(a, bn1, nA[1][mt], 0, 0, 0);
            }
        }
        {
            bf16x8 br0 = *(const bf16x8*)&wsHh[(size_t)((0*16 + 2*w+0)*8 + ks)*512 + lane*8];
            bf16x8 br1 = *(const bf16x8*)&wsHh[(size_t)((0*16 + 2*w+1)*8 + ks)*512 + lane*8];
            bf16x8 bz0 = *(const bf16x8*)&wsHh[(size_t)((1*16 + 2*w+0)*8 + ks)*512 + lane*8];
            bf16x8 bz1 = *(const bf16x8*)&wsHh[(size_t)((1*16 + 2*w+1)*8 + ks)*512 + lane*8];
            bf16x8 bh0 = *(const bf16x8*)&wsHh[(size_t)((2*16 + 2*w+0)*8 + ks)*512 + lane*8];
            bf16x8 bh1 = *(const bf16x8*)&wsHh[(size_t)((2*16 + 2*w+1)*8 + ks)*512 + lane*8];
            #pragma unroll
            for (int mt = 0; mt < 4; ++mt) {
                bf16x8 a = *(const bf16x8*)&afl[(mt*16 + col16)*NFP + ks*32 + kg*8];
                rA[0][mt] = __builtin_amdgcn_mfma_f32_16x16x32_bf16(a, br0, rA[0][mt], 0, 0, 0);
                rA[1][mt] = __builtin_amdgcn_mfma_f32_16x16x32_bf16(a, br1, rA[1][mt], 0, 0, 0);
                zA[0][mt] = __builtin_amdgcn_mfma_f32_16x16x32_bf16(a, bz0, zA[0][mt], 0, 0, 0);
                zA[1][mt] = __builtin_amdgcn_mfma_f32_16x16x32_bf16(a, bz1, zA[1][mt], 0, 0, 0);
                hA[0][mt] = __builtin_amdgcn_mfma_f32_16x16x32_bf16(a, bh0, hA[0][mt], 0, 0, 0);
                hA[1][mt] = __builtin_amdgcn_mfma_f32_16x16x32_bf16(a, bh1, hA[1][mt], 0, 0, 0);
            }
        }
    }
    #pragma unroll
    for (int q = 0; q < 2; ++q) {
        int f = w*32 + q*16 + col16;
        #pragma unroll
        for (int mt = 0; mt < 4; ++mt)
            #pragma unroll
            for (int jj = 0; jj < 4; ++jj) {
                int a = mt*16 + kg*4 + jj;
                float r = sigm(rA[q][mt][jj]);
                float z = sigm(zA[q][mt][jj]);
                float n = tanhf(nA[q][mt][jj] + r*hA[q][mt][jj]);
                float h = bf2f(afl[a*NFP + f]);
                float o = (1.f - z)*n + z*h;
                out[(size_t)(g0+a)*F + f] = fmaxf(o, 0.f);
            }
    }
}

extern "C" void kernel_launch(void* const* d_in, const int* in_sizes, int n_in,
                              void* d_out, int out_size, void* d_ws, size_t ws_size,
                              hipStream_t stream) {
    const float* atom_list = (const float*)d_in[0];
    const float* bond_list = (const float*)d_in[1];
    const int*   adeg      = (const int*)  d_in[2];
    const int*   bdeg      = (const int*)  d_in[3];
    const float* W_atom  = (const float*)d_in[5];
    const float* b_atom  = (const float*)d_in[6];
    const float* W_nbr   = (const float*)d_in[7];
    const float* b_nbr   = (const float*)d_in[8];
    const float* W_align = (const float*)d_in[9];
    const float* b_align = (const float*)d_in[10];
    const float* W_att   = (const float*)d_in[11];
    const float* b_att   = (const float*)d_in[12];
    const float* W_ih    = (const float*)d_in[13];
    const float* b_ih    = (const float*)d_in[14];
    const float* W_hh    = (const float*)d_in[15];
    const float* b_hh    = (const float*)d_in[16];
    float* out = (float*)d_out;

    unsigned short* wsu = (unsigned short*)d_ws;
    float* sumaw        = (float*)((char*)d_ws + WS_SUM);
    unsigned short* wn  = (unsigned short*)((char*)d_ws + WS_WN);

    p0_prep<<<1920, 256, 0, stream>>>(W_atom, W_nbr, W_att, W_ih, W_hh, wsu);
    k2_nbr<<<(Bsz*Lm)/TB, NT2, 0, stream>>>(atom_list, bond_list, adeg, bdeg,
                                            W_align, b_align, b_atom, b_nbr,
                                            wsu, wn, sumaw);
    k4_gru<<<(Bsz*Lm)/K4A, NTK4, 0, stream>>>(wsu, wn, atom_list, sumaw,
                                              b_atom, b_att, b_ih, b_hh, out);
}

// Round 5
// 233.106 us; speedup vs baseline: 29.0381x; 1.2406x over previous
//
#include <hip/hip_runtime.h>
#include <math.h>

#define Bsz 512
#define Lm  128
#define Mn  6
#define AD  39
#define BDm 10
#define KN  49          // AD+BDm
#define F   256
#define TB  16
#define NR  96          // TB*Mn
#define NFP 264         // padded nf/af/wn/ctx row stride (ushorts)
#define ANP 72          // padded A-row stride (ushorts), K padded to 64

// ws byte offsets
#define WS_WATM 0
#define WS_WNBR 32768
#define WS_WATT 65536
#define WS_WIH  196608
#define WS_WHH  589824
#define WS_SUM  983040
#define WS_WN   1245184

typedef __attribute__((ext_vector_type(8))) short bf16x8;
typedef __attribute__((ext_vector_type(4))) float f32x4;

__device__ __forceinline__ float lrelu(float x){ return x > 0.0f ? x : 0.01f*x; }
__device__ __forceinline__ float sigm(float x){ return 1.0f/(1.0f+expf(-x)); }
__device__ __forceinline__ unsigned short f2bf(float f){
    unsigned int u = __builtin_bit_cast(unsigned int, f);
    u += 0x7fffu + ((u>>16)&1u);
    return (unsigned short)(u>>16);
}
__device__ __forceinline__ float bf2f(unsigned short h){
    unsigned int u = ((unsigned int)h)<<16;
    return __builtin_bit_cast(float, u);
}

// ---------------- P0: weights -> bf16 fragment-major ----------------
// frag: elem e = lane*8+j; n = nt*16+(lane&15); k = ks*32+(lane>>4)*8+j
__global__ __launch_bounds__(256)
void p0_prep(const float* __restrict__ Watm, const float* __restrict__ Wnbr,
             const float* __restrict__ Watt, const float* __restrict__ Wih,
             const float* __restrict__ Whh,  unsigned short* __restrict__ ws)
{
    int id = blockIdx.x*256 + threadIdx.x;
    if (id >= 960*512) return;
    int T = id >> 9, e = id & 511;
    int lane = e >> 3, j = e & 7;
    int col16 = lane & 15, kg = lane >> 4;
    float v; unsigned short* dst;
    if (T < 32) {                 // W_atom [256][39], 16 nt x 2 ks, K pad 64
        int nt = T >> 1, ks = T & 1;
        int k = ks*32 + kg*8 + j;
        v = (k < AD) ? Watm[(nt*16 + col16)*AD + k] : 0.0f;
        dst = ws + (WS_WATM>>1) + (size_t)T*512 + e;
    } else if (T < 64) {          // W_nbr [256][49], pad 64
        int T2 = T - 32;
        int nt = T2 >> 1, ks = T2 & 1;
        int k = ks*32 + kg*8 + j;
        v = (k < KN) ? Wnbr[(nt*16 + col16)*KN + k] : 0.0f;
        dst = ws + (WS_WNBR>>1) + (size_t)T2*512 + e;
    } else if (T < 192) {         // W_att [256][256], 16 x 8
        int T2 = T - 64;
        int nt = T2 >> 3, ks = T2 & 7;
        v = Watt[(nt*16 + col16)*F + ks*32 + kg*8 + j];
        dst = ws + (WS_WATT>>1) + (size_t)T2*512 + e;
    } else if (T < 576) {         // W_ih [768][256], 48 x 8
        int T3 = T - 192;
        int nt = T3 >> 3, ks = T3 & 7;
        v = Wih[(nt*16 + col16)*F + ks*32 + kg*8 + j];
        dst = ws + (WS_WIH>>1) + (size_t)T3*512 + e;
    } else {                      // W_hh [768][256], 48 x 8
        int T4 = T - 576;
        int nt = T4 >> 3, ks = T4 & 7;
        v = Whh[(nt*16 + col16)*F + ks*32 + kg*8 + j];
        dst = ws + (WS_WHH>>1) + (size_t)T4*512 + e;
    }
    *dst = f2bf(v);
}

// ---------------- K2: 8 waves, atom-score MFMA + neighbor MFMA + softmax + wn ----------------
#define NT2 512
__global__ __launch_bounds__(NT2, 6)
void k2_nbr(const float* __restrict__ atom, const float* __restrict__ bond,
            const int* __restrict__ adeg_g, const int* __restrict__ bdeg_g,
            const float* __restrict__ Walign, const float* __restrict__ balign,
            const float* __restrict__ batom,  const float* __restrict__ bnbr,
            const unsigned short* __restrict__ ws,
            unsigned short* __restrict__ wn_g, float* __restrict__ sumaw_g)
{
    __shared__ alignas(16) unsigned short nfl[NR*NFP];   // 50688 B; staging overlaid below
    __shared__ float ascl[TB];
    __shared__ float nscl[NR];
    __shared__ float awl[NR];
    __shared__ int   adeg[NR];
    __shared__ int   bdeg[NR];
    unsigned short* arowl = nfl;            // [16][72] overlay (dead before nfl writes)
    unsigned short* anl   = nfl + TB*ANP;   // [96][72] overlay

    const int t  = threadIdx.x;
    const int g0 = blockIdx.x*TB;
    const int molbase = (g0/Lm)*Lm;
    const int w = t >> 6, lane = t & 63;
    const int col16 = lane & 15, kg = lane >> 4;

    // prefetch weight B-fragments (no deps -> overlap gather latency)
    bf16x8 batmf[2][2], bnbrf[2][2];   // [j][ks]
    #pragma unroll
    for (int j = 0; j < 2; ++j)
        #pragma unroll
        for (int ks = 0; ks < 2; ++ks) {
            batmf[j][ks] = *(const bf16x8*)&ws[(WS_WATM>>1) + (size_t)((2*w+j)*2 + ks)*512 + lane*8];
            bnbrf[j][ks] = *(const bf16x8*)&ws[(WS_WNBR>>1) + (size_t)((2*w+j)*2 + ks)*512 + lane*8];
        }

    if (t < NR) {
        adeg[t] = adeg_g[(size_t)g0*Mn + t];
        bdeg[t] = bdeg_g[(size_t)g0*Mn + t];
        nscl[t] = 0.f;
    }
    if (t < TB) ascl[t] = 0.f;
    __syncthreads();   // B0: adeg/bdeg + zeroed accumulators visible

    // stage own rows (pad K 39->64) and neighbor gathers (pad 49->64)
    for (int i = t; i < TB*64; i += NT2) {
        int r = i >> 6, d = i & 63;
        float v = (d < AD) ? atom[(size_t)(g0+r)*AD + d] : 0.f;
        arowl[r*ANP + d] = f2bf(v);
    }
    for (int i = t; i < NR*64; i += NT2) {
        int r = i >> 6, d = i & 63;
        float v = 0.f;
        if (d < AD)      v = atom[(size_t)(molbase + adeg[r])*AD + d];
        else if (d < KN) v = bond[(size_t)(molbase + bdeg[r])*BDm + (d-AD)];
        anl[r*ANP + d] = f2bf(v);
    }
    __syncthreads();   // B1: staging visible

    // ---- atom MFMA -> ascore only (af recomputed in k4); wave w -> nt {2w,2w+1}
    {
        f32x4 acc[2];
        #pragma unroll
        for (int j = 0; j < 2; ++j) acc[j] = (f32x4){0.f,0.f,0.f,0.f};
        #pragma unroll
        for (int ks = 0; ks < 2; ++ks) {
            bf16x8 a = *(const bf16x8*)&arowl[col16*ANP + ks*32 + kg*8];
            #pragma unroll
            for (int j = 0; j < 2; ++j)
                acc[j] = __builtin_amdgcn_mfma_f32_16x16x32_bf16(a, batmf[j][ks], acc[j], 0, 0, 0);
        }
        float ps[4] = {0.f,0.f,0.f,0.f};
        #pragma unroll
        for (int j = 0; j < 2; ++j) {
            const int col = (2*w+j)*16 + col16;
            const float bb  = batom[col];
            const float wal = Walign[col];
            #pragma unroll
            for (int jj = 0; jj < 4; ++jj) ps[jj] += lrelu(acc[j][jj] + bb)*wal;
        }
        #pragma unroll
        for (int jj = 0; jj < 4; ++jj) {
            float p = ps[jj];
            p += __shfl_xor(p, 1); p += __shfl_xor(p, 2);
            p += __shfl_xor(p, 4); p += __shfl_xor(p, 8);
            if (col16 == 0) atomicAdd(&ascl[kg*4 + jj], p);
        }
    }

    // ---- neighbor MFMA (acc in regs across barrier)
    f32x4 acc[6][2];
    #pragma unroll
    for (int mt = 0; mt < 6; ++mt)
        #pragma unroll
        for (int j = 0; j < 2; ++j) acc[mt][j] = (f32x4){0.f,0.f,0.f,0.f};
    #pragma unroll
    for (int ks = 0; ks < 2; ++ks) {
        #pragma unroll
        for (int mt = 0; mt < 6; ++mt) {
            bf16x8 a = *(const bf16x8*)&anl[(mt*16 + col16)*ANP + ks*32 + kg*8];
            #pragma unroll
            for (int j = 0; j < 2; ++j)
                acc[mt][j] = __builtin_amdgcn_mfma_f32_16x16x32_bf16(a, bnbrf[j][ks], acc[mt][j], 0, 0, 0);
        }
    }
    __syncthreads();   // B2: all arowl/anl reads done -> nfl writes safe

    // epilogue: nf -> LDS (bf16), nscore partials
    #pragma unroll
    for (int mt = 0; mt < 6; ++mt) {
        float pns[4] = {0.f,0.f,0.f,0.f};
        #pragma unroll
        for (int j = 0; j < 2; ++j) {
            const int col = (2*w+j)*16 + col16;
            const float bnb  = bnbr[col];
            const float wal2 = Walign[F + col];
            #pragma unroll
            for (int jj = 0; jj < 4; ++jj) {
                float v = lrelu(acc[mt][j][jj] + bnb);
                nfl[(mt*16 + kg*4 + jj)*NFP + col] = f2bf(v);
                pns[jj] += v*wal2;
            }
        }
        #pragma unroll
        for (int jj = 0; jj < 4; ++jj) {
            float p = pns[jj];
            p += __shfl_xor(p, 1); p += __shfl_xor(p, 2);
            p += __shfl_xor(p, 4); p += __shfl_xor(p, 8);
            if (col16 == 0) atomicAdd(&nscl[mt*16 + kg*4 + jj], p);
        }
    }
    __syncthreads();   // B3: nfl + nscl complete

    if (t < TB) {
        const float ba = balign[0];
        const float as = ascl[t];
        float sc[Mn], msk[Mn];
        float mx = -1e30f;
        #pragma unroll
        for (int m = 0; m < Mn; ++m) {
            int pad = (adeg[t*Mn+m] == Lm-1);
            float s = lrelu(as + nscl[t*Mn+m] + ba) + (pad ? -9e8f : 0.0f);
            msk[m] = pad ? 0.f : 1.f;
            sc[m] = s; mx = fmaxf(mx, s);
        }
        float sum = 0.f;
        #pragma unroll
        for (int m = 0; m < Mn; ++m) { sc[m] = expf(sc[m]-mx); sum += sc[m]; }
        const float inv = 1.0f/sum;
        float sa = 0.f;
        #pragma unroll
        for (int m = 0; m < Mn; ++m) { float v = sc[m]*inv*msk[m]; awl[t*Mn+m] = v; sa += v; }
        sumaw_g[g0 + t] = sa;
    }
    __syncthreads();   // B4: awl visible

    // wn[a][:] = sum_m aw*nf -- one (a, 8-col group) per thread
    {
        const int a = t & 15, cg = t >> 4;     // cg in [0,32)
        float o[8] = {0,0,0,0,0,0,0,0};
        #pragma unroll
        for (int m = 0; m < Mn; ++m) {
            const float aw = awl[a*Mn + m];
            uint4 v = *(const uint4*)&nfl[(a*Mn+m)*NFP + cg*8];
            unsigned int d0 = v.x, d1 = v.y, d2 = v.z, d3 = v.w;
            o[0] += aw*__builtin_bit_cast(float, d0<<16);
            o[1] += aw*__builtin_bit_cast(float, d0 & 0xffff0000u);
            o[2] += aw*__builtin_bit_cast(float, d1<<16);
            o[3] += aw*__builtin_bit_cast(float, d1 & 0xffff0000u);
            o[4] += aw*__builtin_bit_cast(float, d2<<16);
            o[5] += aw*__builtin_bit_cast(float, d2 & 0xffff0000u);
            o[6] += aw*__builtin_bit_cast(float, d3<<16);
            o[7] += aw*__builtin_bit_cast(float, d3 & 0xffff0000u);
        }
        uint4 pv;
        pv.x = (unsigned int)f2bf(o[0]) | ((unsigned int)f2bf(o[1])<<16);
        pv.y = (unsigned int)f2bf(o[2]) | ((unsigned int)f2bf(o[3])<<16);
        pv.z = (unsigned int)f2bf(o[4]) | ((unsigned int)f2bf(o[5])<<16);
        pv.w = (unsigned int)f2bf(o[6]) | ((unsigned int)f2bf(o[7])<<16);
        *(uint4*)&wn_g[(size_t)(g0+a)*F + cg*8] = pv;
    }
}

// ---------------- K4: af MFMA + ctx GEMM + 6-way GRU GEMM + gates ----------------
#define NTK4 512
#define K4A  64
__global__ __launch_bounds__(NTK4)
void k4_gru(const unsigned short* __restrict__ ws,
            const unsigned short* __restrict__ wn_g,
            const float* __restrict__ atom,
            const float* __restrict__ sumaw_g, const float* __restrict__ batom,
            const float* __restrict__ batt,
            const float* __restrict__ bih, const float* __restrict__ bhh,
            float* __restrict__ out)
{
    __shared__ alignas(16) unsigned short wnl[K4A*NFP];   // 33792 B; ctxl overlays after phase1
    __shared__ alignas(16) unsigned short afl[K4A*NFP];   // 33792 B
    __shared__ alignas(16) unsigned short arowl[K4A*ANP]; // 9216 B
    __shared__ float sumawl[K4A];
    const int t  = threadIdx.x;
    const int g0 = blockIdx.x*K4A;

    for (int i = t; i < K4A*32; i += NTK4) {
        int row = i >> 5, cg = i & 31;
        *(uint4*)&wnl[row*NFP + cg*8] = *(const uint4*)&wn_g[(size_t)(g0+row)*F + cg*8];
    }
    for (int i = t; i < K4A*64; i += NTK4) {
        int r = i >> 6, d = i & 63;
        float v = (d < AD) ? atom[(size_t)(g0+r)*AD + d] : 0.f;
        arowl[r*ANP + d] = f2bf(v);
    }
    if (t < K4A) sumawl[t] = sumaw_g[g0 + t];
    __syncthreads();   // B1

    const int w = t >> 6, lane = t & 63;
    const int col16 = lane & 15, kg = lane >> 4;
    const unsigned short* wsAtm = ws + (WS_WATM>>1);
    const unsigned short* wsAtt = ws + (WS_WATT>>1);
    const unsigned short* wsIh  = ws + (WS_WIH>>1);
    const unsigned short* wsHh  = ws + (WS_WHH>>1);

    // ---- phase 0: af = lrelu(arow @ Watom^T + b); wave w -> nt {2w, 2w+1}
    {
        f32x4 a0[4], a1[4];
        #pragma unroll
        for (int mt = 0; mt < 4; ++mt) { a0[mt] = (f32x4){0,0,0,0}; a1[mt] = (f32x4){0,0,0,0}; }
        #pragma unroll
        for (int ks = 0; ks < 2; ++ks) {
            bf16x8 b0 = *(const bf16x8*)&wsAtm[(size_t)((2*w)*2   + ks)*512 + lane*8];
            bf16x8 b1 = *(const bf16x8*)&wsAtm[(size_t)((2*w+1)*2 + ks)*512 + lane*8];
            #pragma unroll
            for (int mt = 0; mt < 4; ++mt) {
                bf16x8 a = *(const bf16x8*)&arowl[(mt*16 + col16)*ANP + ks*32 + kg*8];
                a0[mt] = __builtin_amdgcn_mfma_f32_16x16x32_bf16(a, b0, a0[mt], 0, 0, 0);
                a1[mt] = __builtin_amdgcn_mfma_f32_16x16x32_bf16(a, b1, a1[mt], 0, 0, 0);
            }
        }
        const float bb0 = batom[(2*w)*16   + col16];
        const float bb1 = batom[(2*w+1)*16 + col16];
        #pragma unroll
        for (int mt = 0; mt < 4; ++mt)
            #pragma unroll
            for (int jj = 0; jj < 4; ++jj) {
                int row = mt*16 + kg*4 + jj;
                afl[row*NFP + (2*w)*16   + col16] = f2bf(lrelu(a0[mt][jj] + bb0));
                afl[row*NFP + (2*w+1)*16 + col16] = f2bf(lrelu(a1[mt][jj] + bb1));
            }
    }

    // ---- phase 1: ctx = elu(wn @ Watt^T + b_att*sumaw); wave w -> nt {2w, 2w+1}
    f32x4 c0[4], c1[4];
    {
        const float bb0 = batt[(2*w)*16   + col16];
        const float bb1 = batt[(2*w+1)*16 + col16];
        #pragma unroll
        for (int mt = 0; mt < 4; ++mt)
            #pragma unroll
            for (int jj = 0; jj < 4; ++jj) {
                float sa = sumawl[mt*16 + kg*4 + jj];
                c0[mt][jj] = bb0*sa; c1[mt][jj] = bb1*sa;
            }
        #pragma unroll
        for (int ks = 0; ks < 8; ++ks) {
            bf16x8 b0 = *(const bf16x8*)&wsAtt[(size_t)((2*w)*8   + ks)*512 + lane*8];
            bf16x8 b1 = *(const bf16x8*)&wsAtt[(size_t)((2*w+1)*8 + ks)*512 + lane*8];
            #pragma unroll
            for (int mt = 0; mt < 4; ++mt) {
                bf16x8 a = *(const bf16x8*)&wnl[(mt*16 + col16)*NFP + ks*32 + kg*8];
                c0[mt] = __builtin_amdgcn_mfma_f32_16x16x32_bf16(a, b0, c0[mt], 0, 0, 0);
                c1[mt] = __builtin_amdgcn_mfma_f32_16x16x32_bf16(a, b1, c1[mt], 0, 0, 0);
            }
        }
    }
    __syncthreads();   // B2: all wnl reads done -> ctx overlay safe
    unsigned short* ctxl = wnl;
    #pragma unroll
    for (int mt = 0; mt < 4; ++mt)
        #pragma unroll
        for (int jj = 0; jj < 4; ++jj) {
            int row = mt*16 + kg*4 + jj;
            float x0 = c0[mt][jj]; x0 = (x0 > 0.f) ? x0 : expm1f(x0);
            float x1 = c1[mt][jj]; x1 = (x1 > 0.f) ? x1 : expm1f(x1);
            ctxl[row*NFP + (2*w)*16   + col16] = f2bf(x0);
            ctxl[row*NFP + (2*w+1)*16 + col16] = f2bf(x1);
        }
    __syncthreads();   // B3: ctxl visible

    // ---- phase 2: GRU gate GEMMs; wave w -> feature slice w*32..w*32+31
    f32x4 rA[2][4], zA[2][4], nA[2][4], hA[2][4];
    {
        float rb[2], zb[2], nb[2], hb[2];
        #pragma unroll
        for (int q = 0; q < 2; ++q) {
            int f = w*32 + q*16 + col16;
            rb[q] = bih[f]       + bhh[f];
            zb[q] = bih[F + f]   + bhh[F + f];
            nb[q] = bih[2*F + f];
            hb[q] = bhh[2*F + f];
        }
        #pragma unroll
        for (int q = 0; q < 2; ++q)
            #pragma unroll
            for (int mt = 0; mt < 4; ++mt)
                #pragma unroll
                for (int jj = 0; jj < 4; ++jj) {
                    rA[q][mt][jj] = rb[q]; zA[q][mt][jj] = zb[q];
                    nA[q][mt][jj] = nb[q]; hA[q][mt][jj] = hb[q];
                }
    }
    #pragma unroll
    for (int ks = 0; ks < 8; ++ks) {
        {
            bf16x8 br0 = *(const bf16x8*)&wsIh[(size_t)((0*16 + 2*w+0)*8 + ks)*512 + lane*8];
            bf16x8 br1 = *(const bf16x8*)&wsIh[(size_t)((0*16 + 2*w+1)*8 + ks)*512 + lane*8];
            bf16x8 bz0 = *(const bf16x8*)&wsIh[(size_t)((1*16 + 2*w+0)*8 + ks)*512 + lane*8];
            bf16x8 bz1 = *(const bf16x8*)&wsIh[(size_t)((1*16 + 2*w+1)*8 + ks)*512 + lane*8];
            bf16x8 bn0 = *(const bf16x8*)&wsIh[(size_t)((2*16 + 2*w+0)*8 + ks)*512 + lane*8];
            bf16x8 bn1 = *(const bf16x8*)&wsIh[(size_t)((2*16 + 2*w+1)*8 + ks)*512 + lane*8];
            #pragma unroll
            for (int mt = 0; mt < 4; ++mt) {
                bf16x8 a = *(const bf16x8*)&ctxl[(mt*16 + col16)*NFP + ks*32 + kg*8];
                rA[0][mt] = __builtin_amdgcn_mfma_f32_16x16x32_bf16(a, br0, rA[0][mt], 0, 0, 0);
                rA[1][mt] = __builtin_amdgcn_mfma_f32_16x16x32_bf16(a, br1, rA[1][mt], 0, 0, 0);
                zA[0][mt] = __builtin_amdgcn_mfma_f32_16x16x32_bf16(a, bz0, zA[0][mt], 0, 0, 0);
                zA[1][mt] = __builtin_amdgcn_mfma_f32_16x16x32_bf16(a, bz1, zA[1][mt], 0, 0, 0);
                nA[0][mt] = __builtin_amdgcn_mfma_f32_16x16x32_bf16(a, bn0, nA[0][mt], 0, 0, 0);
                nA[1][mt] = __builtin_amdgcn_mfma_f32_16x16x32_bf16(a, bn1, nA[1][mt], 0, 0, 0);
            }
        }
        {
            bf16x8 br0 = *(const bf16x8*)&wsHh[(size_t)((0*16 + 2*w+0)*8 + ks)*512 + lane*8];
            bf16x8 br1 = *(const bf16x8*)&wsHh[(size_t)((0*16 + 2*w+1)*8 + ks)*512 + lane*8];
            bf16x8 bz0 = *(const bf16x8*)&wsHh[(size_t)((1*16 + 2*w+0)*8 + ks)*512 + lane*8];
            bf16x8 bz1 = *(const bf16x8*)&wsHh[(size_t)((1*16 + 2*w+1)*8 + ks)*512 + lane*8];
            bf16x8 bh0 = *(const bf16x8*)&wsHh[(size_t)((2*16 + 2*w+0)*8 + ks)*512 + lane*8];
            bf16x8 bh1 = *(const bf16x8*)&wsHh[(size_t)((2*16 + 2*w+1)*8 + ks)*512 + lane*8];
            #pragma unroll
            for (int mt = 0; mt < 4; ++mt) {
                bf16x8 a = *(const bf16x8*)&afl[(mt*16 + col16)*NFP + ks*32 + kg*8];
                rA[0][mt] = __builtin_amdgcn_mfma_f32_16x16x32_bf16(a, br0, rA[0][mt], 0, 0, 0);
                rA[1][mt] = __builtin_amdgcn_mfma_f32_16x16x32_bf16(a, br1, rA[1][mt], 0, 0, 0);
                zA[0][mt] = __builtin_amdgcn_mfma_f32_16x16x32_bf16(a, bz0, zA[0][mt], 0, 0, 0);
                zA[1][mt] = __builtin_amdgcn_mfma_f32_16x16x32_bf16(a, bz1, zA[1][mt], 0, 0, 0);
                hA[0][mt] = __builtin_amdgcn_mfma_f32_16x16x32_bf16(a, bh0, hA[0][mt], 0, 0, 0);
                hA[1][mt] = __builtin_amdgcn_mfma_f32_16x16x32_bf16(a, bh1, hA[1][mt], 0, 0, 0);
            }
        }
    }
    #pragma unroll
    for (int q = 0; q < 2; ++q) {
        int f = w*32 + q*16 + col16;
        #pragma unroll
        for (int mt = 0; mt < 4; ++mt)
            #pragma unroll
            for (int jj = 0; jj < 4; ++jj) {
                int a = mt*16 + kg*4 + jj;
                float r = sigm(rA[q][mt][jj]);
                float z = sigm(zA[q][mt][jj]);
                float n = tanhf(nA[q][mt][jj] + r*hA[q][mt][jj]);
                float h = bf2f(afl[a*NFP + f]);
                float o = (1.f - z)*n + z*h;
                out[(size_t)(g0+a)*F + f] = fmaxf(o, 0.f);
            }
    }
}

extern "C" void kernel_launch(void* const* d_in, const int* in_sizes, int n_in,
                              void* d_out, int out_size, void* d_ws, size_t ws_size,
                              hipStream_t stream) {
    const float* atom_list = (const float*)d_in[0];
    const float* bond_list = (const float*)d_in[1];
    const int*   adeg      = (const int*)  d_in[2];
    const int*   bdeg      = (const int*)  d_in[3];
    const float* W_atom  = (const float*)d_in[5];
    const float* b_atom  = (const float*)d_in[6];
    const float* W_nbr   = (const float*)d_in[7];
    const float* b_nbr   = (const float*)d_in[8];
    const float* W_align = (const float*)d_in[9];
    const float* b_align = (const float*)d_in[10];
    const float* W_att   = (const float*)d_in[11];
    const float* b_att   = (const float*)d_in[12];
    const float* W_ih    = (const float*)d_in[13];
    const float* b_ih    = (const float*)d_in[14];
    const float* W_hh    = (const float*)d_in[15];
    const float* b_hh    = (const float*)d_in[16];
    float* out = (float*)d_out;

    unsigned short* wsu = (unsigned short*)d_ws;
    float* sumaw        = (float*)((char*)d_ws + WS_SUM);
    unsigned short* wn  = (unsigned short*)((char*)d_ws + WS_WN);

    p0_prep<<<1920, 256, 0, stream>>>(W_atom, W_nbr, W_att, W_ih, W_hh, wsu);
    k2_nbr<<<(Bsz*Lm)/TB, NT2, 0, stream>>>(atom_list, bond_list, adeg, bdeg,
                                            W_align, b_align, b_atom, b_nbr,
                                            wsu, wn, sumaw);
    k4_gru<<<(Bsz*Lm)/K4A, NTK4, 0, stream>>>(wsu, wn, atom_list, sumaw,
                                              b_atom, b_att, b_ih, b_hh, out);
}